// Round 10
// baseline (474.199 us; speedup 1.0000x reference)
//
#include <hip/hip_runtime.h>
#include <cstdint>
#include <cmath>

#define NB 4
#define NS 2048
#define ND 2048
#define NH 16
#define NDH 128
#define NM (NB*NS)   // 8192

typedef unsigned short u16;
typedef __bf16 bf16x8 __attribute__((ext_vector_type(8)));
typedef u16    u16x8  __attribute__((ext_vector_type(8)));
typedef u16    u16x4  __attribute__((ext_vector_type(4)));
typedef float  f32x4  __attribute__((ext_vector_type(4)));
typedef float  f32x16 __attribute__((ext_vector_type(16)));
typedef unsigned u32x4_t __attribute__((ext_vector_type(4)));

__device__ __forceinline__ u16 f2bf(float f) {
  unsigned u = __float_as_uint(f);
  u += 0x7fffu + ((u >> 16) & 1u);   // RNE
  return (u16)(u >> 16);
}
__device__ __forceinline__ float bf2f(u16 h) {
  return __uint_as_float(((unsigned)h) << 16);
}
__device__ __forceinline__ void gld16(const void* g, void* l) {
  __builtin_amdgcn_global_load_lds((__attribute__((address_space(1))) void*)g,
                                   (__attribute__((address_space(3))) void*)l,
                                   16, 0, 0);
}
__device__ __forceinline__ f32x16 mfma32_bf16(bf16x8 a, bf16x8 b, f32x16 c) {
  return __builtin_amdgcn_mfma_f32_32x32x16_bf16(a, b, c, 0, 0, 0);
}
__device__ __forceinline__ unsigned cvtpk(float lo, float hi) {
  unsigned r;
  asm("v_cvt_pk_bf16_f32 %0, %1, %2" : "=v"(r) : "v"(lo), "v"(hi));
  return r;
}
__device__ __forceinline__ void p32swap(unsigned &a, unsigned &b) {
  asm volatile("v_permlane32_swap_b32 %0, %1" : "+v"(a), "+v"(b));
}

// ---------------- fp32 -> bf16 convert (8 elems/thread) ----------------
__global__ void cvt_bf16_kernel(const float* __restrict__ in, u16* __restrict__ out, int n8) {
  int i = blockIdx.x * 256 + threadIdx.x;
  if (i >= n8) return;
  const float4* p = (const float4*)in + (size_t)i * 2;
  float4 a = p[0], b = p[1];
  u16x8 r;
  r[0]=f2bf(a.x); r[1]=f2bf(a.y); r[2]=f2bf(a.z); r[3]=f2bf(a.w);
  r[4]=f2bf(b.x); r[5]=f2bf(b.y); r[6]=f2bf(b.z); r[7]=f2bf(b.w);
  ((u16x8*)out)[i] = r;
}

// ---------------- RoPE tables: cos/sin [S][64] ----------------
__global__ void rope_tables_kernel(float* __restrict__ cosT, float* __restrict__ sinT) {
  int s = blockIdx.x, d = threadIdx.x;
  double inv = pow(10000.0, -(double)d / 64.0);
  float ang = (float)((double)s * inv);
  cosT[s*64 + d] = cosf(ang);
  sinT[s*64 + d] = sinf(ang);
}

// ---------------- RoPE apply, in place on bf16 [NM][ND] ----------------
__global__ void rope_apply_kernel(u16* __restrict__ X, const float* __restrict__ cosT,
                                  const float* __restrict__ sinT) {
  int idx = blockIdx.x * 256 + threadIdx.x;
  int pc = idx & 7, h = (idx >> 3) & (NH - 1), m = idx >> 7;
  int s = m & (NS - 1);
  int d0 = pc * 8;
  size_t base = (size_t)m * ND + h * NDH + d0;
  u16x8 v0 = *(const u16x8*)(X + base);
  u16x8 v1 = *(const u16x8*)(X + base + 64);
  u16x8 r0, r1;
#pragma unroll
  for (int j = 0; j < 8; ++j) {
    float c  = cosT[s*64 + d0 + j];
    float sn = sinT[s*64 + d0 + j];
    float x0 = bf2f(v0[j]), x1 = bf2f(v1[j]);
    r0[j] = f2bf(x0 * c - x1 * sn);
    r1[j] = f2bf(x1 * c + x0 * sn);
  }
  *(u16x8*)(X + base)      = r0;
  *(u16x8*)(X + base + 64) = r1;
}

// ---------------- bf16 GEMM, 256x256 tile, 8-phase, 32x32x16 MFMA ----------
// R10: (1) QKV fused — grid = nmat*256, block bid>>8 selects (Bw, C); makes
// the GEMM the longest dispatch so rocprof top-5 finally shows its counters.
// (2) mfma_f32_32x32x16 (m119: 2495 TF ceiling vs 2075 for 16x16, and half
// the MFMA instruction count).  Wave tile 128x64 = 4 rowfrags x 2 colfrags
// of 32x32; acc = 4x2 f32x16 = 128 VGPR.  A/B frag layout (row/col=lane&31,
// k=(lane>>5)*8) and C/D map ((reg&3)+8*(reg>>2)+4*hi) as verified in attn.
// Staging/ledger unchanged from R8: vmcnt(4) at phases 4/8 only.
#define BARX do { __builtin_amdgcn_s_barrier(); __builtin_amdgcn_sched_barrier(0); } while (0)
#define VM4  do { asm volatile("s_waitcnt vmcnt(4)" ::: "memory"); \
                  __builtin_amdgcn_sched_barrier(0); } while (0)
#define GP(BUF, KS, MH, LOADB, WAITV, STAGE) do {                                 \
  bf16x8 afr[2][2];                                                               \
  rdA(afr, BUF, KS, MH);                                                          \
  if (LOADB) rdB(bfr, BUF, KS);                                                   \
  STAGE;                                                                          \
  mm(afr, bfr, MH);                                                               \
  if (WAITV) VM4;                                                                 \
  BARX;                                                                           \
} while (0)

template <typename OutT>
__global__ __launch_bounds__(512, 2) void gemm256_kernel(
    const u16* __restrict__ A,
    const u16* __restrict__ B0, const u16* __restrict__ B1, const u16* __restrict__ B2,
    OutT* __restrict__ C0, OutT* __restrict__ C1, OutT* __restrict__ C2,
    int Nd, int Kd) {
  __shared__ __align__(16) char Asb[65536];
  __shared__ __align__(16) char Bsb[65536];
  int tid = threadIdx.x;
  int wave = tid >> 6, lane = tid & 63;
  int ql = lane & 31, hi = lane >> 5;
  int wr = wave >> 2, wc = wave & 3;           // 2 x 4 wave grid
  int w  = (int)blockIdx.x >> 8;               // matrix select (fused QKV)
  int tb = (int)blockIdx.x & 255;
  const u16* Bw = (w == 0) ? B0 : (w == 1) ? B1 : B2;
  OutT*      C  = (w == 0) ? C0 : (w == 1) ? C1 : C2;
  int NTn = Nd >> 8;
  int swz = (tb & 7) * 32 + (tb >> 3);         // XCD swizzle over 256 tiles
  int m0 = (swz / NTn) << 8, n0 = (swz % NTn) << 8;

  // staging per-lane constants (slab [256 rows][32 k] bf16, 64 B rows,
  // swizzle byte ^= (row&3)<<4 via pre-swizzled global source)
  int srow = wave * 16 + (lane >> 2);
  int scswz = ((lane & 3) * 16) ^ ((srow & 3) << 4);
  size_t rowB = (size_t)Kd * 2;
  const char* Asrc = (const char*)A  + (size_t)(m0 + srow) * rowB + scswz;
  const char* Bsrc = (const char*)Bw + (size_t)(n0 + srow) * rowB + scswz;
  char* Adst = Asb + wave * 1024;
  char* Bdst = Bsb + wave * 1024;
  size_t half2 = rowB << 7;                    // +128 rows

  auto stageA = [&](int buf, int ks, int tile) {
    const char* s = Asrc + (size_t)tile * 128 + ks * 64;
    char* d = Adst + buf * 32768 + ks * 16384;
    gld16(s, d);
    gld16(s + half2, d + 8192);
  };
  auto stageB = [&](int buf, int ks, int tile) {
    const char* s = Bsrc + (size_t)tile * 128 + ks * 64;
    char* d = Bdst + buf * 32768 + ks * 16384;
    gld16(s, d);
    gld16(s + half2, d + 8192);
  };

  f32x16 acc[4][2] = {};
  bf16x8 bfr[2][2];

  auto rdA = [&](bf16x8 (&dst)[2][2], int buf, int ks, int mh) {
#pragma unroll
    for (int rf = 0; rf < 2; ++rf) {
      int row = wr*128 + mh*64 + rf*32 + ql;
      int rs = (row & 3) << 4;
#pragma unroll
      for (int kst = 0; kst < 2; ++kst)
        dst[rf][kst] = *(const bf16x8*)(Asb + buf*32768 + ks*16384 + row*64
                                        + ((kst*32 + hi*16) ^ rs));
    }
  };
  auto rdB = [&](bf16x8 (&dst)[2][2], int buf, int ks) {
#pragma unroll
    for (int cf = 0; cf < 2; ++cf) {
      int row = wc*64 + cf*32 + ql;
      int rs = (row & 3) << 4;
#pragma unroll
      for (int kst = 0; kst < 2; ++kst)
        dst[cf][kst] = *(const bf16x8*)(Bsb + buf*32768 + ks*16384 + row*64
                                        + ((kst*32 + hi*16) ^ rs));
    }
  };
  auto mm = [&](bf16x8 (&a)[2][2], bf16x8 (&bf_)[2][2], int mh) {
    __builtin_amdgcn_s_setprio(1);
#pragma unroll
    for (int kst = 0; kst < 2; ++kst)
#pragma unroll
      for (int rf = 0; rf < 2; ++rf)
#pragma unroll
        for (int cf = 0; cf < 2; ++cf)
          acc[mh*2+rf][cf] = mfma32_bf16(a[rf][kst], bf_[cf][kst], acc[mh*2+rf][cf]);
    __builtin_amdgcn_s_setprio(0);
  };

  int NKT = Kd >> 6;          // K-tiles of 64
  int NIT = NKT >> 1;         // 2 tiles per iteration

  // prologue: tile0 fully + tile1 ks0 (12 loads); vmcnt(4) -> tile0 landed
  stageA(0, 0, 0); stageA(0, 1, 0); stageB(0, 0, 0); stageB(0, 1, 0);
  stageA(1, 0, 1); stageB(1, 0, 1);
  asm volatile("s_waitcnt vmcnt(4)" ::: "memory");
  __builtin_amdgcn_sched_barrier(0);
  BARX;

  for (int j = 0; j < NIT; ++j) {
    int t1  = 2*j + 1;
    int tn0 = (2*j + 2) & (NKT - 1);   // wraps on final iters (garbage, unconsumed)
    int tn1 = (2*j + 3) & (NKT - 1);
    GP(0, 0, 0, true,  false, { stageA(1, 1, t1);  });
    GP(0, 0, 1, false, false, { stageB(1, 1, t1);  });
    GP(0, 1, 1, true,  false, { stageA(0, 0, tn0); });
    GP(0, 1, 0, false, true,  { stageB(0, 0, tn0); });
    GP(1, 0, 0, true,  false, { stageA(0, 1, tn0); });
    GP(1, 0, 1, false, false, { stageB(0, 1, tn0); });
    GP(1, 1, 1, true,  false, { stageA(1, 0, tn1); });
    GP(1, 1, 0, false, true,  { stageB(1, 0, tn1); });
  }
  asm volatile("s_waitcnt vmcnt(0)" ::: "memory");   // drain dangling stages

  // epilogue: C/D map col = lane&31, row = (reg&3)+8*(reg>>2)+4*hi [m74/m101]
  int rbase = m0 + wr*128;
  int cbase = n0 + wc*64 + ql;
#pragma unroll
  for (int g = 0; g < 4; ++g)
#pragma unroll
    for (int cf = 0; cf < 2; ++cf)
#pragma unroll
      for (int r = 0; r < 16; ++r) {
        int crow = (r & 3) + 8*(r >> 2) + 4*hi;
        size_t off = (size_t)(rbase + g*32 + crow) * Nd + (cbase + cf*32);
        if constexpr (sizeof(OutT) == 2) C[off] = f2bf(acc[g][cf][r]);
        else                             C[off] = acc[g][cf][r];
      }
}

// ---------------- causal flash attention, 32x32 swapped-QK^T ----------------
__global__ __launch_bounds__(512, 2) void flash_attn_kernel(
    const u16* __restrict__ Q, const u16* __restrict__ K, const u16* __restrict__ V,
    u16* __restrict__ O) {
  __shared__ __align__(16) u16 Ks[2*64*128];  // 32 KB swizzled [kv][dh]
  __shared__ __align__(16) u16 Vt[2*128*64];  // 32 KB swizzled [dh][kv]
  int tid = threadIdx.x, wv = tid >> 6, lane = tid & 63;
  int ql = lane & 31, hi = lane >> 5;
  int b = blockIdx.x >> 4, h = blockIdx.x & 15;
  int qt = (int)gridDim.y - 1 - (int)blockIdx.y;
  int q0 = qt << 8;
  int qw = q0 + wv*32;          // wave q base
  int qa = qw + ql;             // this lane's q row
  int swzl = (ql & 7) << 4;     // LDS XOR swizzle for this lane's rows
  const float qscale = 0.08838834764831845f * 1.4426950408889634f; // /sqrt(128)*log2e

  bf16x8 qf[8];
  {
    const u16* qp = Q + (size_t)(b*NS + qa) * ND + h*NDH + hi*8;
#pragma unroll
    for (int ds = 0; ds < 8; ++ds) {
      u16x8 t = *(const u16x8*)(qp + ds*16);
      u16x8 r;
#pragma unroll
      for (int j = 0; j < 8; ++j) r[j] = f2bf(bf2f(t[j]) * qscale);
      qf[ds] = *(bf16x8*)&r;
    }
  }
  f32x16 o0 = {}, o1 = {}, o2 = {}, o3 = {};   // O dh-subtiles 0..3
  float m_run = -INFINITY, l_run = 0.f;

  const char* Kg = (const char*)(K + (size_t)b*NS*ND + h*NDH);
  const char* Vg = (const char*)(V + (size_t)b*NS*ND + h*NDH);
  const int ROWB = ND * 2;

  int p   = tid & 31;    // dh pair for V repack
  int kvg = tid >> 5;    // kv chunk 0..15 (4 kv rows each)

  auto issueKV = [&](int kv0, int buf, unsigned (&dlo)[4], unsigned (&dhi)[4]) {
    const char* vrow = Vg + (size_t)(kv0 + kvg*4) * ROWB;
#pragma unroll
    for (int j = 0; j < 4; ++j) {
      dlo[j] = *(const unsigned*)(vrow + j*ROWB + p*4);
      dhi[j] = *(const unsigned*)(vrow + j*ROWB + 128 + p*4);
    }
    char* ksb = (char*)Ks + buf*16384;
#pragma unroll
    for (int c = 0; c < 2; ++c) {
      int s = c*8192 + wv*1024 + lane*16;
      int row = s >> 8;
      int within = (s & 255) ^ ((row & 7) << 4);
      gld16(Kg + (size_t)(kv0 + row)*ROWB + within, ksb + c*8192 + wv*1024);
    }
    __builtin_amdgcn_sched_barrier(0);
  };

  auto dostep = [&](int kv0, int buf, const unsigned (&dlo)[4], const unsigned (&dhi)[4],
                    bool hasNext) {
    if (hasNext) asm volatile("s_waitcnt vmcnt(10)" ::: "memory");
    else         asm volatile("s_waitcnt vmcnt(0)"  ::: "memory");
    __builtin_amdgcn_sched_barrier(0);
    __builtin_amdgcn_s_barrier();        // BAR-A: all waves' K(t) landed
    __builtin_amdgcn_sched_barrier(0);

    char* vtb = (char*)Vt + buf*16384;
    const char* ksb = (const char*)Ks + buf*16384;

    {
      u16x4 rA, rB, rC, rD;
#pragma unroll
      for (int j = 0; j < 4; ++j) {
        rA[j] = (u16)dlo[j]; rB[j] = (u16)(dlo[j] >> 16);
        rC[j] = (u16)dhi[j]; rD[j] = (u16)(dhi[j] >> 16);
      }
      int a0 = ((2*p   )*128 + kvg*8) ^ (((2*p  ) & 7) << 4);
      int a1 = ((2*p+ 1)*128 + kvg*8) ^ (((2*p+1) & 7) << 4);
      int a2 = ((2*p+64)*128 + kvg*8) ^ (((2*p  ) & 7) << 4);
      int a3 = ((2*p+65)*128 + kvg*8) ^ (((2*p+1) & 7) << 4);
      *(u16x4*)(vtb + a0) = rA;
      *(u16x4*)(vtb + a1) = rB;
      *(u16x4*)(vtb + a2) = rC;
      *(u16x4*)(vtb + a3) = rD;
    }

    // S = K Q^T (swapped): p0 = kv 0..31, p1 = kv 32..63; lane's q = ql
    f32x16 p0 = {}, p1 = {};
    __builtin_amdgcn_s_setprio(1);
#pragma unroll
    for (int ds = 0; ds < 8; ++ds) {
      bf16x8 kf0 = *(const bf16x8*)(ksb + ((ql*256 + ds*32 + hi*16) ^ swzl));
      p0 = mfma32_bf16(kf0, qf[ds], p0);
      bf16x8 kf1 = *(const bf16x8*)(ksb + (((32+ql)*256 + ds*32 + hi*16) ^ swzl));
      p1 = mfma32_bf16(kf1, qf[ds], p1);
    }
    __builtin_amdgcn_s_setprio(0);

    // causal mask
    if (kv0 + 63 > qw) {
      int thresh = qa - kv0 - 4*hi;
#pragma unroll
      for (int r = 0; r < 16; ++r) {
        int c0 = (r & 3) + 8*(r >> 2);
        p0[r] = (c0      > thresh) ? -INFINITY : p0[r];
        p1[r] = (c0 + 32 > thresh) ? -INFINITY : p1[r];
      }
    }

    // row max (in-reg tree + one cross-pair shuffle)
    float mx[16];
#pragma unroll
    for (int r = 0; r < 16; ++r) mx[r] = fmaxf(p0[r], p1[r]);
#pragma unroll
    for (int s = 8; s > 0; s >>= 1)
#pragma unroll
      for (int r = 0; r < 8; ++r) if (r < s) mx[r] = fmaxf(mx[r], mx[r + s]);
    float pmax = fmaxf(mx[0], __shfl_xor(mx[0], 32, 64));

    // T13 defer-max
    if (!__all(pmax <= m_run + 8.f)) {
      float mn = fmaxf(m_run, pmax);
      float corr = __builtin_amdgcn_exp2f(m_run - mn);
      m_run = mn; l_run *= corr;
#pragma unroll
      for (int r = 0; r < 16; ++r) {
        float cw = __shfl(corr, (r & 3) + 8*(r >> 2) + 4*hi, 64);
        o0[r] *= cw; o1[r] *= cw; o2[r] *= cw; o3[r] *= cw;
      }
    }

    // exp2 + row sum
    float sm[16];
#pragma unroll
    for (int r = 0; r < 16; ++r) {
      p0[r] = __builtin_amdgcn_exp2f(p0[r] - m_run);
      p1[r] = __builtin_amdgcn_exp2f(p1[r] - m_run);
      sm[r] = p0[r] + p1[r];
    }
#pragma unroll
    for (int s = 8; s > 0; s >>= 1)
#pragma unroll
      for (int r = 0; r < 8; ++r) if (r < s) sm[r] += sm[r + s];
    l_run += sm[0] + __shfl_xor(sm[0], 32, 64);

    // P -> bf16 A-frags: 16 cvt_pk + 8 permlane32_swap (T12)
    bf16x8 pa0, pa1, pa2, pa3;
#define MKPA(P, B, OUT) {                              \
      unsigned a0 = cvtpk(P[(B)+0], P[(B)+1]);         \
      unsigned b0 = cvtpk(P[(B)+4], P[(B)+5]);         \
      p32swap(a0, b0);                                 \
      unsigned a1 = cvtpk(P[(B)+2], P[(B)+3]);         \
      unsigned b1 = cvtpk(P[(B)+6], P[(B)+7]);         \
      p32swap(a1, b1);                                 \
      u32x4_t w; w[0]=a0; w[1]=a1; w[2]=b0; w[3]=b1;   \
      OUT = *(bf16x8*)&w; }
    MKPA(p0, 0, pa0)
    MKPA(p0, 8, pa1)
    MKPA(p1, 0, pa2)
    MKPA(p1, 8, pa3)
#undef MKPA

    asm volatile("s_waitcnt lgkmcnt(0)" ::: "memory");  // my Vt writes done
    __builtin_amdgcn_sched_barrier(0);
    __builtin_amdgcn_s_barrier();        // BAR-B: all waves' Vt[buf] visible
    __builtin_amdgcn_sched_barrier(0);

    // O += P V
    __builtin_amdgcn_s_setprio(1);
#define PVT(OT, T) {                                                        \
      _Pragma("unroll")                                                     \
      for (int ks = 0; ks < 4; ++ks) {                                      \
        int a = ((((T)*32 + ql)*128 + ks*32 + hi*16) ^ swzl);               \
        bf16x8 vf = *(const bf16x8*)(vtb + a);                              \
        OT = mfma32_bf16(ks==0?pa0:ks==1?pa1:ks==2?pa2:pa3, vf, OT);        \
      } }
    PVT(o0, 0)
    PVT(o1, 1)
    PVT(o2, 2)
    PVT(o3, 3)
#undef PVT
    __builtin_amdgcn_s_setprio(0);
  };

  int nt = 4*qt + 4;                     // kv tiles 0 .. q0+255
  unsigned dloA[4], dhiA[4], dloB[4], dhiB[4];
  issueKV(0, 0, dloA, dhiA);
  for (int t = 0; ; t += 2) {
    bool h1 = (t+1 < nt);
    if (h1) issueKV((t+1)*64, 1, dloB, dhiB);
    dostep(t*64, 0, dloA, dhiA, h1);
    if (!h1) break;
    bool h2 = (t+2 < nt);
    if (h2) issueKV((t+2)*64, 0, dloA, dhiA);
    dostep((t+1)*64, 1, dloB, dhiB, h2);
    if (!h2) break;
  }

  // epilogue
  float inv = 1.0f / l_run;
#pragma unroll
  for (int r = 0; r < 16; ++r) {
    int crow = (r & 3) + 8*(r >> 2) + 4*hi;
    float iv = __shfl(inv, crow, 64);
    size_t base = (size_t)(b*NS + qw + crow) * ND + h*NDH + ql;
    O[base +  0] = f2bf(o0[r] * iv);
    O[base + 32] = f2bf(o1[r] * iv);
    O[base + 64] = f2bf(o2[r] * iv);
    O[base + 96] = f2bf(o3[r] * iv);
  }
}

// ---------------- launch ----------------
extern "C" void kernel_launch(void* const* d_in, const int* in_sizes, int n_in,
                              void* d_out, int out_size, void* d_ws, size_t ws_size,
                              hipStream_t stream) {
  const float* x  = (const float*)d_in[0];
  // d_in[1] = attn_mask (causal, handled analytically)
  const float* Wq = (const float*)d_in[2];
  const float* Wk = (const float*)d_in[3];
  const float* Wv = (const float*)d_in[4];
  const float* Wo = (const float*)d_in[5];

  char* ws = (char*)d_ws;
  const size_t SZ_MD = (size_t)NM * ND * 2;
  const size_t SZ_W  = (size_t)ND * ND * 2;
  u16* xb  = (u16*)(ws);
  u16* Qb  = (u16*)(ws + SZ_MD);
  u16* Kb  = (u16*)(ws + 2*SZ_MD);
  u16* Vb  = (u16*)(ws + 3*SZ_MD);
  u16* Ab  = (u16*)(ws + 4*SZ_MD);
  u16* Wqb = (u16*)(ws + 5*SZ_MD);
  u16* Wkb = (u16*)(ws + 5*SZ_MD + SZ_W);
  u16* Wvb = (u16*)(ws + 5*SZ_MD + 2*SZ_W);
  u16* Wob = (u16*)(ws + 5*SZ_MD + 3*SZ_W);
  float* cosT = (float*)(ws + 5*SZ_MD + 4*SZ_W);
  float* sinT = (float*)(ws + 5*SZ_MD + 4*SZ_W + (size_t)NS*64*4);
  size_t needed = 5*SZ_MD + 4*SZ_W + 2*(size_t)NS*64*4;
  if (ws_size < needed) return;

  {
    int n8 = (NM * ND) / 8;
    cvt_bf16_kernel<<<(n8 + 255)/256, 256, 0, stream>>>(x, xb, n8);
    int w8 = (ND * ND) / 8;
    cvt_bf16_kernel<<<(w8 + 255)/256, 256, 0, stream>>>(Wq, Wqb, w8);
    cvt_bf16_kernel<<<(w8 + 255)/256, 256, 0, stream>>>(Wk, Wkb, w8);
    cvt_bf16_kernel<<<(w8 + 255)/256, 256, 0, stream>>>(Wv, Wvb, w8);
    cvt_bf16_kernel<<<(w8 + 255)/256, 256, 0, stream>>>(Wo, Wob, w8);
  }
  rope_tables_kernel<<<NS, 64, 0, stream>>>(cosT, sinT);

  // fused QKV projection: one dispatch, 768 blocks
  gemm256_kernel<u16><<<3*256, 512, 0, stream>>>(xb, Wqb, Wkb, Wvb,
                                                 Qb, Kb, Vb, ND, ND);

  {
    int nthr = NM * NH * 8;
    rope_apply_kernel<<<nthr/256, 256, 0, stream>>>(Qb, cosT, sinT);
    rope_apply_kernel<<<nthr/256, 256, 0, stream>>>(Kb, cosT, sinT);
  }

  flash_attn_kernel<<<dim3(NB*NH, NS/256), 512, 0, stream>>>(Qb, Kb, Vb, Ab);

  gemm256_kernel<float><<<256, 512, 0, stream>>>(Ab, Wob, nullptr, nullptr,
                                                 (float*)d_out, nullptr, nullptr, ND, ND);
}

// Round 11
// 441.558 us; speedup vs baseline: 1.0739x; 1.0739x over previous
//
#include <hip/hip_runtime.h>
#include <cstdint>
#include <cmath>

#define NB 4
#define NS 2048
#define ND 2048
#define NH 16
#define NDH 128
#define NM (NB*NS)   // 8192

typedef unsigned short u16;
typedef __bf16 bf16x8 __attribute__((ext_vector_type(8)));
typedef u16    u16x8  __attribute__((ext_vector_type(8)));
typedef u16    u16x4  __attribute__((ext_vector_type(4)));
typedef float  f32x4  __attribute__((ext_vector_type(4)));
typedef float  f32x16 __attribute__((ext_vector_type(16)));
typedef unsigned u32x4_t __attribute__((ext_vector_type(4)));

__device__ __forceinline__ u16 f2bf(float f) {
  unsigned u = __float_as_uint(f);
  u += 0x7fffu + ((u >> 16) & 1u);   // RNE
  return (u16)(u >> 16);
}
__device__ __forceinline__ float bf2f(u16 h) {
  return __uint_as_float(((unsigned)h) << 16);
}
__device__ __forceinline__ void gld16(const void* g, void* l) {
  __builtin_amdgcn_global_load_lds((__attribute__((address_space(1))) void*)g,
                                   (__attribute__((address_space(3))) void*)l,
                                   16, 0, 0);
}
__device__ __forceinline__ f32x16 mfma32_bf16(bf16x8 a, bf16x8 b, f32x16 c) {
  return __builtin_amdgcn_mfma_f32_32x32x16_bf16(a, b, c, 0, 0, 0);
}
__device__ __forceinline__ unsigned cvtpk(float lo, float hi) {
  unsigned r;
  asm("v_cvt_pk_bf16_f32 %0, %1, %2" : "=v"(r) : "v"(lo), "v"(hi));
  return r;
}
__device__ __forceinline__ void p32swap(unsigned &a, unsigned &b) {
  asm volatile("v_permlane32_swap_b32 %0, %1" : "+v"(a), "+v"(b));
}

// ---------------- fp32 -> bf16 convert (8 elems/thread) ----------------
__global__ void cvt_bf16_kernel(const float* __restrict__ in, u16* __restrict__ out, int n8) {
  int i = blockIdx.x * 256 + threadIdx.x;
  if (i >= n8) return;
  const float4* p = (const float4*)in + (size_t)i * 2;
  float4 a = p[0], b = p[1];
  u16x8 r;
  r[0]=f2bf(a.x); r[1]=f2bf(a.y); r[2]=f2bf(a.z); r[3]=f2bf(a.w);
  r[4]=f2bf(b.x); r[5]=f2bf(b.y); r[6]=f2bf(b.z); r[7]=f2bf(b.w);
  ((u16x8*)out)[i] = r;
}

// ---------------- RoPE tables: cos/sin [S][64] ----------------
__global__ void rope_tables_kernel(float* __restrict__ cosT, float* __restrict__ sinT) {
  int s = blockIdx.x, d = threadIdx.x;
  double inv = pow(10000.0, -(double)d / 64.0);
  float ang = (float)((double)s * inv);
  cosT[s*64 + d] = cosf(ang);
  sinT[s*64 + d] = sinf(ang);
}

// ---------------- RoPE apply, in place on bf16 [NM][ND] ----------------
__global__ void rope_apply_kernel(u16* __restrict__ X, const float* __restrict__ cosT,
                                  const float* __restrict__ sinT) {
  int idx = blockIdx.x * 256 + threadIdx.x;
  int pc = idx & 7, h = (idx >> 3) & (NH - 1), m = idx >> 7;
  int s = m & (NS - 1);
  int d0 = pc * 8;
  size_t base = (size_t)m * ND + h * NDH + d0;
  u16x8 v0 = *(const u16x8*)(X + base);
  u16x8 v1 = *(const u16x8*)(X + base + 64);
  u16x8 r0, r1;
#pragma unroll
  for (int j = 0; j < 8; ++j) {
    float c  = cosT[s*64 + d0 + j];
    float sn = sinT[s*64 + d0 + j];
    float x0 = bf2f(v0[j]), x1 = bf2f(v1[j]);
    r0[j] = f2bf(x0 * c - x1 * sn);
    r1[j] = f2bf(x1 * c + x0 * sn);
  }
  *(u16x8*)(X + base)      = r0;
  *(u16x8*)(X + base + 64) = r1;
}

// ---------------- bf16 GEMM, 256x256 tile, 8-phase, 32x32x16 MFMA ----------
// R11: LDS swizzle fixed — rows are 64 B (bank phase 16*(row&1)), so swizzle
// bits must be row bits 1..2: swz(row)=((row>>1)&3)<<4.  Each 8-lane group
// (consecutive rows) then covers all 32 banks exactly once per b128 read
// (R10's (row&3)<<4 gave a 4-way conflict: SQ_LDS_BANK_CONFLICT 5.66e7,
// ~35% of dispatch cycles).  Staging source pre-swizzled identically
// (linear gld16 dest; rule: same involution on both sides).
#define BARX do { __builtin_amdgcn_s_barrier(); __builtin_amdgcn_sched_barrier(0); } while (0)
#define VM4  do { asm volatile("s_waitcnt vmcnt(4)" ::: "memory"); \
                  __builtin_amdgcn_sched_barrier(0); } while (0)
#define GP(BUF, KS, MH, LOADB, WAITV, STAGE) do {                                 \
  bf16x8 afr[2][2];                                                               \
  rdA(afr, BUF, KS, MH);                                                          \
  if (LOADB) rdB(bfr, BUF, KS);                                                   \
  STAGE;                                                                          \
  mm(afr, bfr, MH);                                                               \
  if (WAITV) VM4;                                                                 \
  BARX;                                                                           \
} while (0)

template <typename OutT>
__global__ __launch_bounds__(512, 2) void gemm256_kernel(
    const u16* __restrict__ A,
    const u16* __restrict__ B0, const u16* __restrict__ B1, const u16* __restrict__ B2,
    OutT* __restrict__ C0, OutT* __restrict__ C1, OutT* __restrict__ C2,
    int Nd, int Kd) {
  __shared__ __align__(16) char Asb[65536];
  __shared__ __align__(16) char Bsb[65536];
  int tid = threadIdx.x;
  int wave = tid >> 6, lane = tid & 63;
  int ql = lane & 31, hi = lane >> 5;
  int wr = wave >> 2, wc = wave & 3;           // 2 x 4 wave grid
  int w  = (int)blockIdx.x >> 8;               // matrix select (fused QKV)
  int tb = (int)blockIdx.x & 255;
  const u16* Bw = (w == 0) ? B0 : (w == 1) ? B1 : B2;
  OutT*      C  = (w == 0) ? C0 : (w == 1) ? C1 : C2;
  int NTn = Nd >> 8;
  int swz = (tb & 7) * 32 + (tb >> 3);         // XCD swizzle over 256 tiles
  int m0 = (swz / NTn) << 8, n0 = (swz % NTn) << 8;

  // staging per-lane constants (slab [256 rows][64 B]; physical byte p in
  // row r holds logical col p ^ ((r>>1)&3)<<4)
  int srow = wave * 16 + (lane >> 2);
  int scswz = ((lane & 3) * 16) ^ (((srow >> 1) & 3) << 4);
  size_t rowB = (size_t)Kd * 2;
  const char* Asrc = (const char*)A  + (size_t)(m0 + srow) * rowB + scswz;
  const char* Bsrc = (const char*)Bw + (size_t)(n0 + srow) * rowB + scswz;
  char* Adst = Asb + wave * 1024;
  char* Bdst = Bsb + wave * 1024;
  size_t half2 = rowB << 7;                    // +128 rows (128%4==0: same swz)

  auto stageA = [&](int buf, int ks, int tile) {
    const char* s = Asrc + (size_t)tile * 128 + ks * 64;
    char* d = Adst + buf * 32768 + ks * 16384;
    gld16(s, d);
    gld16(s + half2, d + 8192);
  };
  auto stageB = [&](int buf, int ks, int tile) {
    const char* s = Bsrc + (size_t)tile * 128 + ks * 64;
    char* d = Bdst + buf * 32768 + ks * 16384;
    gld16(s, d);
    gld16(s + half2, d + 8192);
  };

  f32x16 acc[4][2] = {};
  bf16x8 bfr[2][2];

  auto rdA = [&](bf16x8 (&dst)[2][2], int buf, int ks, int mh) {
#pragma unroll
    for (int rf = 0; rf < 2; ++rf) {
      int row = wr*128 + mh*64 + rf*32 + ql;
      int rs = ((row >> 1) & 3) << 4;
#pragma unroll
      for (int kst = 0; kst < 2; ++kst)
        dst[rf][kst] = *(const bf16x8*)(Asb + buf*32768 + ks*16384 + row*64
                                        + ((kst*32 + hi*16) ^ rs));
    }
  };
  auto rdB = [&](bf16x8 (&dst)[2][2], int buf, int ks) {
#pragma unroll
    for (int cf = 0; cf < 2; ++cf) {
      int row = wc*64 + cf*32 + ql;
      int rs = ((row >> 1) & 3) << 4;
#pragma unroll
      for (int kst = 0; kst < 2; ++kst)
        dst[cf][kst] = *(const bf16x8*)(Bsb + buf*32768 + ks*16384 + row*64
                                        + ((kst*32 + hi*16) ^ rs));
    }
  };
  auto mm = [&](bf16x8 (&a)[2][2], bf16x8 (&bf_)[2][2], int mh) {
    __builtin_amdgcn_s_setprio(1);
#pragma unroll
    for (int kst = 0; kst < 2; ++kst)
#pragma unroll
      for (int rf = 0; rf < 2; ++rf)
#pragma unroll
        for (int cf = 0; cf < 2; ++cf)
          acc[mh*2+rf][cf] = mfma32_bf16(a[rf][kst], bf_[cf][kst], acc[mh*2+rf][cf]);
    __builtin_amdgcn_s_setprio(0);
  };

  int NKT = Kd >> 6;          // K-tiles of 64
  int NIT = NKT >> 1;         // 2 tiles per iteration

  // prologue: tile0 fully + tile1 ks0 (12 loads); vmcnt(4) -> tile0 landed
  stageA(0, 0, 0); stageA(0, 1, 0); stageB(0, 0, 0); stageB(0, 1, 0);
  stageA(1, 0, 1); stageB(1, 0, 1);
  asm volatile("s_waitcnt vmcnt(4)" ::: "memory");
  __builtin_amdgcn_sched_barrier(0);
  BARX;

  for (int j = 0; j < NIT; ++j) {
    int t1  = 2*j + 1;
    int tn0 = (2*j + 2) & (NKT - 1);   // wraps on final iters (garbage, unconsumed)
    int tn1 = (2*j + 3) & (NKT - 1);
    GP(0, 0, 0, true,  false, { stageA(1, 1, t1);  });
    GP(0, 0, 1, false, false, { stageB(1, 1, t1);  });
    GP(0, 1, 1, true,  false, { stageA(0, 0, tn0); });
    GP(0, 1, 0, false, true,  { stageB(0, 0, tn0); });
    GP(1, 0, 0, true,  false, { stageA(0, 1, tn0); });
    GP(1, 0, 1, false, false, { stageB(0, 1, tn0); });
    GP(1, 1, 1, true,  false, { stageA(1, 0, tn1); });
    GP(1, 1, 0, false, true,  { stageB(1, 0, tn1); });
  }
  asm volatile("s_waitcnt vmcnt(0)" ::: "memory");   // drain dangling stages

  // epilogue: C/D map col = lane&31, row = (reg&3)+8*(reg>>2)+4*hi [m74/m101]
  int rbase = m0 + wr*128;
  int cbase = n0 + wc*64 + ql;
#pragma unroll
  for (int g = 0; g < 4; ++g)
#pragma unroll
    for (int cf = 0; cf < 2; ++cf)
#pragma unroll
      for (int r = 0; r < 16; ++r) {
        int crow = (r & 3) + 8*(r >> 2) + 4*hi;
        size_t off = (size_t)(rbase + g*32 + crow) * Nd + (cbase + cf*32);
        if constexpr (sizeof(OutT) == 2) C[off] = f2bf(acc[g][cf][r]);
        else                             C[off] = acc[g][cf][r];
      }
}

// ---------------- causal flash attention, 32x32 swapped-QK^T ----------------
__global__ __launch_bounds__(512, 2) void flash_attn_kernel(
    const u16* __restrict__ Q, const u16* __restrict__ K, const u16* __restrict__ V,
    u16* __restrict__ O) {
  __shared__ __align__(16) u16 Ks[2*64*128];  // 32 KB swizzled [kv][dh]
  __shared__ __align__(16) u16 Vt[2*128*64];  // 32 KB swizzled [dh][kv]
  int tid = threadIdx.x, wv = tid >> 6, lane = tid & 63;
  int ql = lane & 31, hi = lane >> 5;
  int b = blockIdx.x >> 4, h = blockIdx.x & 15;
  int qt = (int)gridDim.y - 1 - (int)blockIdx.y;
  int q0 = qt << 8;
  int qw = q0 + wv*32;          // wave q base
  int qa = qw + ql;             // this lane's q row
  int swzl = (ql & 7) << 4;     // LDS XOR swizzle for this lane's rows
  const float qscale = 0.08838834764831845f * 1.4426950408889634f; // /sqrt(128)*log2e

  bf16x8 qf[8];
  {
    const u16* qp = Q + (size_t)(b*NS + qa) * ND + h*NDH + hi*8;
#pragma unroll
    for (int ds = 0; ds < 8; ++ds) {
      u16x8 t = *(const u16x8*)(qp + ds*16);
      u16x8 r;
#pragma unroll
      for (int j = 0; j < 8; ++j) r[j] = f2bf(bf2f(t[j]) * qscale);
      qf[ds] = *(bf16x8*)&r;
    }
  }
  f32x16 o0 = {}, o1 = {}, o2 = {}, o3 = {};   // O dh-subtiles 0..3
  float m_run = -INFINITY, l_run = 0.f;

  const char* Kg = (const char*)(K + (size_t)b*NS*ND + h*NDH);
  const char* Vg = (const char*)(V + (size_t)b*NS*ND + h*NDH);
  const int ROWB = ND * 2;

  int p   = tid & 31;    // dh pair for V repack
  int kvg = tid >> 5;    // kv chunk 0..15 (4 kv rows each)

  auto issueKV = [&](int kv0, int buf, unsigned (&dlo)[4], unsigned (&dhi)[4]) {
    const char* vrow = Vg + (size_t)(kv0 + kvg*4) * ROWB;
#pragma unroll
    for (int j = 0; j < 4; ++j) {
      dlo[j] = *(const unsigned*)(vrow + j*ROWB + p*4);
      dhi[j] = *(const unsigned*)(vrow + j*ROWB + 128 + p*4);
    }
    char* ksb = (char*)Ks + buf*16384;
#pragma unroll
    for (int c = 0; c < 2; ++c) {
      int s = c*8192 + wv*1024 + lane*16;
      int row = s >> 8;
      int within = (s & 255) ^ ((row & 7) << 4);
      gld16(Kg + (size_t)(kv0 + row)*ROWB + within, ksb + c*8192 + wv*1024);
    }
    __builtin_amdgcn_sched_barrier(0);
  };

  auto dostep = [&](int kv0, int buf, const unsigned (&dlo)[4], const unsigned (&dhi)[4],
                    bool hasNext) {
    if (hasNext) asm volatile("s_waitcnt vmcnt(10)" ::: "memory");
    else         asm volatile("s_waitcnt vmcnt(0)"  ::: "memory");
    __builtin_amdgcn_sched_barrier(0);
    __builtin_amdgcn_s_barrier();        // BAR-A: all waves' K(t) landed
    __builtin_amdgcn_sched_barrier(0);

    char* vtb = (char*)Vt + buf*16384;
    const char* ksb = (const char*)Ks + buf*16384;

    {
      u16x4 rA, rB, rC, rD;
#pragma unroll
      for (int j = 0; j < 4; ++j) {
        rA[j] = (u16)dlo[j]; rB[j] = (u16)(dlo[j] >> 16);
        rC[j] = (u16)dhi[j]; rD[j] = (u16)(dhi[j] >> 16);
      }
      int a0 = ((2*p   )*128 + kvg*8) ^ (((2*p  ) & 7) << 4);
      int a1 = ((2*p+ 1)*128 + kvg*8) ^ (((2*p+1) & 7) << 4);
      int a2 = ((2*p+64)*128 + kvg*8) ^ (((2*p  ) & 7) << 4);
      int a3 = ((2*p+65)*128 + kvg*8) ^ (((2*p+1) & 7) << 4);
      *(u16x4*)(vtb + a0) = rA;
      *(u16x4*)(vtb + a1) = rB;
      *(u16x4*)(vtb + a2) = rC;
      *(u16x4*)(vtb + a3) = rD;
    }

    // S = K Q^T (swapped): p0 = kv 0..31, p1 = kv 32..63; lane's q = ql
    f32x16 p0 = {}, p1 = {};
    __builtin_amdgcn_s_setprio(1);
#pragma unroll
    for (int ds = 0; ds < 8; ++ds) {
      bf16x8 kf0 = *(const bf16x8*)(ksb + ((ql*256 + ds*32 + hi*16) ^ swzl));
      p0 = mfma32_bf16(kf0, qf[ds], p0);
      bf16x8 kf1 = *(const bf16x8*)(ksb + (((32+ql)*256 + ds*32 + hi*16) ^ swzl));
      p1 = mfma32_bf16(kf1, qf[ds], p1);
    }
    __builtin_amdgcn_s_setprio(0);

    // causal mask
    if (kv0 + 63 > qw) {
      int thresh = qa - kv0 - 4*hi;
#pragma unroll
      for (int r = 0; r < 16; ++r) {
        int c0 = (r & 3) + 8*(r >> 2);
        p0[r] = (c0      > thresh) ? -INFINITY : p0[r];
        p1[r] = (c0 + 32 > thresh) ? -INFINITY : p1[r];
      }
    }

    // row max (in-reg tree + one cross-pair shuffle)
    float mx[16];
#pragma unroll
    for (int r = 0; r < 16; ++r) mx[r] = fmaxf(p0[r], p1[r]);
#pragma unroll
    for (int s = 8; s > 0; s >>= 1)
#pragma unroll
      for (int r = 0; r < 8; ++r) if (r < s) mx[r] = fmaxf(mx[r], mx[r + s]);
    float pmax = fmaxf(mx[0], __shfl_xor(mx[0], 32, 64));

    // T13 defer-max
    if (!__all(pmax <= m_run + 8.f)) {
      float mn = fmaxf(m_run, pmax);
      float corr = __builtin_amdgcn_exp2f(m_run - mn);
      m_run = mn; l_run *= corr;
#pragma unroll
      for (int r = 0; r < 16; ++r) {
        float cw = __shfl(corr, (r & 3) + 8*(r >> 2) + 4*hi, 64);
        o0[r] *= cw; o1[r] *= cw; o2[r] *= cw; o3[r] *= cw;
      }
    }

    // exp2 + row sum
    float sm[16];
#pragma unroll
    for (int r = 0; r < 16; ++r) {
      p0[r] = __builtin_amdgcn_exp2f(p0[r] - m_run);
      p1[r] = __builtin_amdgcn_exp2f(p1[r] - m_run);
      sm[r] = p0[r] + p1[r];
    }
#pragma unroll
    for (int s = 8; s > 0; s >>= 1)
#pragma unroll
      for (int r = 0; r < 8; ++r) if (r < s) sm[r] += sm[r + s];
    l_run += sm[0] + __shfl_xor(sm[0], 32, 64);

    // P -> bf16 A-frags: 16 cvt_pk + 8 permlane32_swap (T12)
    bf16x8 pa0, pa1, pa2, pa3;
#define MKPA(P, B, OUT) {                              \
      unsigned a0 = cvtpk(P[(B)+0], P[(B)+1]);         \
      unsigned b0 = cvtpk(P[(B)+4], P[(B)+5]);         \
      p32swap(a0, b0);                                 \
      unsigned a1 = cvtpk(P[(B)+2], P[(B)+3]);         \
      unsigned b1 = cvtpk(P[(B)+6], P[(B)+7]);         \
      p32swap(a1, b1);                                 \
      u32x4_t w; w[0]=a0; w[1]=a1; w[2]=b0; w[3]=b1;   \
      OUT = *(bf16x8*)&w; }
    MKPA(p0, 0, pa0)
    MKPA(p0, 8, pa1)
    MKPA(p1, 0, pa2)
    MKPA(p1, 8, pa3)
#undef MKPA

    asm volatile("s_waitcnt lgkmcnt(0)" ::: "memory");  // my Vt writes done
    __builtin_amdgcn_sched_barrier(0);
    __builtin_amdgcn_s_barrier();        // BAR-B: all waves' Vt[buf] visible
    __builtin_amdgcn_sched_barrier(0);

    // O += P V
    __builtin_amdgcn_s_setprio(1);
#define PVT(OT, T) {                                                        \
      _Pragma("unroll")                                                     \
      for (int ks = 0; ks < 4; ++ks) {                                      \
        int a = ((((T)*32 + ql)*128 + ks*32 + hi*16) ^ swzl);               \
        bf16x8 vf = *(const bf16x8*)(vtb + a);                              \
        OT = mfma32_bf16(ks==0?pa0:ks==1?pa1:ks==2?pa2:pa3, vf, OT);        \
      } }
    PVT(o0, 0)
    PVT(o1, 1)
    PVT(o2, 2)
    PVT(o3, 3)
#undef PVT
    __builtin_amdgcn_s_setprio(0);
  };

  int nt = 4*qt + 4;                     // kv tiles 0 .. q0+255
  unsigned dloA[4], dhiA[4], dloB[4], dhiB[4];
  issueKV(0, 0, dloA, dhiA);
  for (int t = 0; ; t += 2) {
    bool h1 = (t+1 < nt);
    if (h1) issueKV((t+1)*64, 1, dloB, dhiB);
    dostep(t*64, 0, dloA, dhiA, h1);
    if (!h1) break;
    bool h2 = (t+2 < nt);
    if (h2) issueKV((t+2)*64, 0, dloA, dhiA);
    dostep((t+1)*64, 1, dloB, dhiB, h2);
    if (!h2) break;
  }

  // epilogue
  float inv = 1.0f / l_run;
#pragma unroll
  for (int r = 0; r < 16; ++r) {
    int crow = (r & 3) + 8*(r >> 2) + 4*hi;
    float iv = __shfl(inv, crow, 64);
    size_t base = (size_t)(b*NS + qw + crow) * ND + h*NDH + ql;
    O[base +  0] = f2bf(o0[r] * iv);
    O[base + 32] = f2bf(o1[r] * iv);
    O[base + 64] = f2bf(o2[r] * iv);
    O[base + 96] = f2bf(o3[r] * iv);
  }
}

// ---------------- launch ----------------
extern "C" void kernel_launch(void* const* d_in, const int* in_sizes, int n_in,
                              void* d_out, int out_size, void* d_ws, size_t ws_size,
                              hipStream_t stream) {
  const float* x  = (const float*)d_in[0];
  // d_in[1] = attn_mask (causal, handled analytically)
  const float* Wq = (const float*)d_in[2];
  const float* Wk = (const float*)d_in[3];
  const float* Wv = (const float*)d_in[4];
  const float* Wo = (const float*)d_in[5];

  char* ws = (char*)d_ws;
  const size_t SZ_MD = (size_t)NM * ND * 2;
  const size_t SZ_W  = (size_t)ND * ND * 2;
  u16* xb  = (u16*)(ws);
  u16* Qb  = (u16*)(ws + SZ_MD);
  u16* Kb  = (u16*)(ws + 2*SZ_MD);
  u16* Vb  = (u16*)(ws + 3*SZ_MD);
  u16* Ab  = (u16*)(ws + 4*SZ_MD);
  u16* Wqb = (u16*)(ws + 5*SZ_MD);
  u16* Wkb = (u16*)(ws + 5*SZ_MD + SZ_W);
  u16* Wvb = (u16*)(ws + 5*SZ_MD + 2*SZ_W);
  u16* Wob = (u16*)(ws + 5*SZ_MD + 3*SZ_W);
  float* cosT = (float*)(ws + 5*SZ_MD + 4*SZ_W);
  float* sinT = (float*)(ws + 5*SZ_MD + 4*SZ_W + (size_t)NS*64*4);
  size_t needed = 5*SZ_MD + 4*SZ_W + 2*(size_t)NS*64*4;
  if (ws_size < needed) return;

  {
    int n8 = (NM * ND) / 8;
    cvt_bf16_kernel<<<(n8 + 255)/256, 256, 0, stream>>>(x, xb, n8);
    int w8 = (ND * ND) / 8;
    cvt_bf16_kernel<<<(w8 + 255)/256, 256, 0, stream>>>(Wq, Wqb, w8);
    cvt_bf16_kernel<<<(w8 + 255)/256, 256, 0, stream>>>(Wk, Wkb, w8);
    cvt_bf16_kernel<<<(w8 + 255)/256, 256, 0, stream>>>(Wv, Wvb, w8);
    cvt_bf16_kernel<<<(w8 + 255)/256, 256, 0, stream>>>(Wo, Wob, w8);
  }
  rope_tables_kernel<<<NS, 64, 0, stream>>>(cosT, sinT);

  // fused QKV projection: one dispatch, 768 blocks
  gemm256_kernel<u16><<<3*256, 512, 0, stream>>>(xb, Wqb, Wkb, Wvb,
                                                 Qb, Kb, Vb, ND, ND);

  {
    int nthr = NM * NH * 8;
    rope_apply_kernel<<<nthr/256, 256, 0, stream>>>(Qb, cosT, sinT);
    rope_apply_kernel<<<nthr/256, 256, 0, stream>>>(Kb, cosT, sinT);
  }

  flash_attn_kernel<<<dim3(NB*NH, NS/256), 512, 0, stream>>>(Qb, Kb, Vb, Ab);

  gemm256_kernel<float><<<256, 512, 0, stream>>>(Ab, Wob, nullptr, nullptr,
                                                 (float*)d_out, nullptr, nullptr, ND, ND);
}

// Round 12
// 419.160 us; speedup vs baseline: 1.1313x; 1.0534x over previous
//
#include <hip/hip_runtime.h>
#include <cstdint>
#include <cmath>

#define NB 4
#define NS 2048
#define ND 2048
#define NH 16
#define NDH 128
#define NM (NB*NS)   // 8192

typedef unsigned short u16;
typedef __bf16 bf16x8 __attribute__((ext_vector_type(8)));
typedef u16    u16x8  __attribute__((ext_vector_type(8)));
typedef u16    u16x4  __attribute__((ext_vector_type(4)));
typedef float  f32x4  __attribute__((ext_vector_type(4)));
typedef float  f32x16 __attribute__((ext_vector_type(16)));
typedef unsigned u32x4_t __attribute__((ext_vector_type(4)));

__device__ __forceinline__ u16 f2bf(float f) {
  unsigned u = __float_as_uint(f);
  u += 0x7fffu + ((u >> 16) & 1u);   // RNE
  return (u16)(u >> 16);
}
__device__ __forceinline__ float bf2f(u16 h) {
  return __uint_as_float(((unsigned)h) << 16);
}
__device__ __forceinline__ void gld16(const void* g, void* l) {
  __builtin_amdgcn_global_load_lds((__attribute__((address_space(1))) void*)g,
                                   (__attribute__((address_space(3))) void*)l,
                                   16, 0, 0);
}
__device__ __forceinline__ f32x4 mfma_bf16(bf16x8 a, bf16x8 b, f32x4 c) {
  return __builtin_amdgcn_mfma_f32_16x16x32_bf16(a, b, c, 0, 0, 0);
}
__device__ __forceinline__ f32x16 mfma32_bf16(bf16x8 a, bf16x8 b, f32x16 c) {
  return __builtin_amdgcn_mfma_f32_32x32x16_bf16(a, b, c, 0, 0, 0);
}
__device__ __forceinline__ unsigned cvtpk(float lo, float hi) {
  unsigned r;
  asm("v_cvt_pk_bf16_f32 %0, %1, %2" : "=v"(r) : "v"(lo), "v"(hi));
  return r;
}
__device__ __forceinline__ void p32swap(unsigned &a, unsigned &b) {
  asm volatile("v_permlane32_swap_b32 %0, %1" : "+v"(a), "+v"(b));
}

// ---------------- fp32 -> bf16 convert (8 elems/thread) ----------------
__global__ void cvt_bf16_kernel(const float* __restrict__ in, u16* __restrict__ out, int n8) {
  int i = blockIdx.x * 256 + threadIdx.x;
  if (i >= n8) return;
  const float4* p = (const float4*)in + (size_t)i * 2;
  float4 a = p[0], b = p[1];
  u16x8 r;
  r[0]=f2bf(a.x); r[1]=f2bf(a.y); r[2]=f2bf(a.z); r[3]=f2bf(a.w);
  r[4]=f2bf(b.x); r[5]=f2bf(b.y); r[6]=f2bf(b.z); r[7]=f2bf(b.w);
  ((u16x8*)out)[i] = r;
}

// ---------------- RoPE tables: cos/sin [S][64] ----------------
__global__ void rope_tables_kernel(float* __restrict__ cosT, float* __restrict__ sinT) {
  int s = blockIdx.x, d = threadIdx.x;
  double inv = pow(10000.0, -(double)d / 64.0);
  float ang = (float)((double)s * inv);
  cosT[s*64 + d] = cosf(ang);
  sinT[s*64 + d] = sinf(ang);
}

// ---------------- RoPE apply, in place on bf16 [NM][ND] ----------------
__global__ void rope_apply_kernel(u16* __restrict__ X, const float* __restrict__ cosT,
                                  const float* __restrict__ sinT) {
  int idx = blockIdx.x * 256 + threadIdx.x;
  int pc = idx & 7, h = (idx >> 3) & (NH - 1), m = idx >> 7;
  int s = m & (NS - 1);
  int d0 = pc * 8;
  size_t base = (size_t)m * ND + h * NDH + d0;
  u16x8 v0 = *(const u16x8*)(X + base);
  u16x8 v1 = *(const u16x8*)(X + base + 64);
  u16x8 r0, r1;
#pragma unroll
  for (int j = 0; j < 8; ++j) {
    float c  = cosT[s*64 + d0 + j];
    float sn = sinT[s*64 + d0 + j];
    float x0 = bf2f(v0[j]), x1 = bf2f(v1[j]);
    r0[j] = f2bf(x0 * c - x1 * sn);
    r1[j] = f2bf(x1 * c + x0 * sn);
  }
  *(u16x8*)(X + base)      = r0;
  *(u16x8*)(X + base + 64) = r1;
}

// ---------------- bf16 GEMM, 256x256 tile, 8-phase, 16x16x32 MFMA ----------
// R12: revert to 16x16x32 (R8's verified frag pattern: li=lane&15 rows,
// lg=lane>>4 K-chunks) + R11's corrected swizzle bits ((row>>1)&3, since
// rows are 64 B and bank phase already carries row bit 0).  Derivation:
// bank start = 16*(row&1) + 4*(lg ^ ((row>>1)&3)-ish) — every 8-lane group
// covers all 32 banks once, for all lg quarters.  Fused QKV (bid>>8 selects
// matrix).  Single barrier/phase, vmcnt(4) at phases 4/8 only.
#define BARX do { __builtin_amdgcn_s_barrier(); __builtin_amdgcn_sched_barrier(0); } while (0)
#define VM4  do { asm volatile("s_waitcnt vmcnt(4)" ::: "memory"); \
                  __builtin_amdgcn_sched_barrier(0); } while (0)
#define GP(BUF, KS, MH, LOADB, WAITV, STAGE) do {                                 \
  bf16x8 af[4];                                                                   \
  _Pragma("unroll")                                                               \
  for (int mf = 0; mf < 4; ++mf)                                                  \
    af[mf] = *(const bf16x8*)(Asb + (BUF)*32768 + (KS)*16384 + arow + ((MH)*4+mf)*1024); \
  if (LOADB) {                                                                    \
    _Pragma("unroll")                                                             \
    for (int nf = 0; nf < 4; ++nf)                                                \
      bfr[nf] = *(const bf16x8*)(Bsb + (BUF)*32768 + (KS)*16384 + brow + nf*1024); \
  }                                                                               \
  STAGE;                                                                          \
  __builtin_amdgcn_s_setprio(1);                                                  \
  _Pragma("unroll")                                                               \
  for (int mf = 0; mf < 4; ++mf)                                                  \
    _Pragma("unroll")                                                             \
    for (int nf = 0; nf < 4; ++nf)                                                \
      acc[(MH)*4+mf][nf] = mfma_bf16(af[mf], bfr[nf], acc[(MH)*4+mf][nf]);        \
  __builtin_amdgcn_s_setprio(0);                                                  \
  if (WAITV) VM4;                                                                 \
  BARX;                                                                           \
} while (0)

template <typename OutT>
__global__ __launch_bounds__(512, 2) void gemm256_kernel(
    const u16* __restrict__ A,
    const u16* __restrict__ B0, const u16* __restrict__ B1, const u16* __restrict__ B2,
    OutT* __restrict__ C0, OutT* __restrict__ C1, OutT* __restrict__ C2,
    int Nd, int Kd) {
  __shared__ __align__(16) char Asb[65536];
  __shared__ __align__(16) char Bsb[65536];
  int tid = threadIdx.x;
  int wave = tid >> 6, lane = tid & 63;
  int li = lane & 15, lg = lane >> 4;
  int wr = wave >> 2, wc = wave & 3;           // 2 x 4 wave grid
  int w  = (int)blockIdx.x >> 8;               // matrix select (fused QKV)
  int tb = (int)blockIdx.x & 255;
  const u16* Bw = (w == 0) ? B0 : (w == 1) ? B1 : B2;
  OutT*      C  = (w == 0) ? C0 : (w == 1) ? C1 : C2;
  int NTn = Nd >> 8;
  int swz = (tb & 7) * 32 + (tb >> 3);         // XCD swizzle over 256 tiles
  int m0 = (swz / NTn) << 8, n0 = (swz % NTn) << 8;

  // ds_read per-lane bases: swizzle keyed on row bits 1..2 (row = ...+li,
  // frag offsets are multiples of 16 rows so li bits carry row bits 1..2)
  int rswz = (lg * 16) ^ (((li >> 1) & 3) << 4);
  int arow = (wr * 128 + li) * 64 + rswz;      // + (MH*4+mf)*1024
  int brow = (wc *  64 + li) * 64 + rswz;      // + nf*1024

  // staging: physical byte p of row r holds logical p ^ (((r>>1)&3)<<4)
  int srow = wave * 16 + (lane >> 2);
  int scswz = ((lane & 3) * 16) ^ (((srow >> 1) & 3) << 4);
  size_t rowB = (size_t)Kd * 2;
  const char* Asrc = (const char*)A  + (size_t)(m0 + srow) * rowB + scswz;
  const char* Bsrc = (const char*)Bw + (size_t)(n0 + srow) * rowB + scswz;
  char* Adst = Asb + wave * 1024;
  char* Bdst = Bsb + wave * 1024;
  size_t half2 = rowB << 7;                    // +128 rows (same swz: 128%4==0)

  auto stageA = [&](int buf, int ks, int tile) {
    const char* s = Asrc + (size_t)tile * 128 + ks * 64;
    char* d = Adst + buf * 32768 + ks * 16384;
    gld16(s, d);
    gld16(s + half2, d + 8192);
  };
  auto stageB = [&](int buf, int ks, int tile) {
    const char* s = Bsrc + (size_t)tile * 128 + ks * 64;
    char* d = Bdst + buf * 32768 + ks * 16384;
    gld16(s, d);
    gld16(s + half2, d + 8192);
  };

  f32x4 acc[8][4] = {};
  bf16x8 bfr[4];

  int NKT = Kd >> 6;          // K-tiles of 64
  int NIT = NKT >> 1;         // 2 tiles per iteration

  // prologue: tile0 fully + tile1 ks0 (12 loads); vmcnt(4) -> tile0 landed
  stageA(0, 0, 0); stageA(0, 1, 0); stageB(0, 0, 0); stageB(0, 1, 0);
  stageA(1, 0, 1); stageB(1, 0, 1);
  asm volatile("s_waitcnt vmcnt(4)" ::: "memory");
  __builtin_amdgcn_sched_barrier(0);
  BARX;

  for (int j = 0; j < NIT; ++j) {
    int t1  = 2*j + 1;
    int tn0 = (2*j + 2) & (NKT - 1);   // wraps on final iters (garbage, unconsumed)
    int tn1 = (2*j + 3) & (NKT - 1);
    GP(0, 0, 0, true,  false, { stageA(1, 1, t1);  });
    GP(0, 0, 1, false, false, { stageB(1, 1, t1);  });
    GP(0, 1, 1, true,  false, { stageA(0, 0, tn0); });
    GP(0, 1, 0, false, true,  { stageB(0, 0, tn0); });
    GP(1, 0, 0, true,  false, { stageA(0, 1, tn0); });
    GP(1, 0, 1, false, false, { stageB(0, 1, tn0); });
    GP(1, 1, 1, true,  false, { stageA(1, 0, tn1); });
    GP(1, 1, 0, false, true,  { stageB(1, 0, tn1); });
  }
  asm volatile("s_waitcnt vmcnt(0)" ::: "memory");   // drain dangling stages

  // epilogue: C layout col = lane&15, row = (lane>>4)*4 + reg  [m89/m91]
  int rbase = m0 + wr*128 + lg*4;
  int cbase = n0 + wc*64 + li;
#pragma unroll
  for (int am = 0; am < 8; ++am)
#pragma unroll
    for (int nf = 0; nf < 4; ++nf)
#pragma unroll
      for (int r = 0; r < 4; ++r) {
        size_t off = (size_t)(rbase + am*16 + r) * Nd + (cbase + nf*16);
        if constexpr (sizeof(OutT) == 2) C[off] = f2bf(acc[am][nf][r]);
        else                             C[off] = acc[am][nf][r];
      }
}

// ---------------- causal flash attention, 32x32 swapped-QK^T ----------------
// R12: Vt swizzle keyed on (row>>1)&7 (both write and PV-read sides).
// Write rows are {2p, 2p+1, 2p+64, 2p+65} -> all map to granule p&7, so each
// write instruction spreads over all 8 16-B granules (was: even rows only ->
// 4 granules -> half-bandwidth, the persistent 1.3e7 conflict count).
// PV reads (consecutive rows T*32+ql) still cover 32 banks per cycle.
// K-path swizzle (ql&7 on 256-B rows) unchanged.
__global__ __launch_bounds__(512, 2) void flash_attn_kernel(
    const u16* __restrict__ Q, const u16* __restrict__ K, const u16* __restrict__ V,
    u16* __restrict__ O) {
  __shared__ __align__(16) u16 Ks[2*64*128];  // 32 KB swizzled [kv][dh]
  __shared__ __align__(16) u16 Vt[2*128*64];  // 32 KB swizzled [dh][kv]
  int tid = threadIdx.x, wv = tid >> 6, lane = tid & 63;
  int ql = lane & 31, hi = lane >> 5;
  int b = blockIdx.x >> 4, h = blockIdx.x & 15;
  int qt = (int)gridDim.y - 1 - (int)blockIdx.y;
  int q0 = qt << 8;
  int qw = q0 + wv*32;          // wave q base
  int qa = qw + ql;             // this lane's q row
  int swzl = (ql & 7) << 4;     // Ks swizzle (256-B rows)
  int vswz = ((ql >> 1) & 7) << 4;  // Vt read swizzle (128-B rows, bits 1..3)
  const float qscale = 0.08838834764831845f * 1.4426950408889634f; // /sqrt(128)*log2e

  bf16x8 qf[8];
  {
    const u16* qp = Q + (size_t)(b*NS + qa) * ND + h*NDH + hi*8;
#pragma unroll
    for (int ds = 0; ds < 8; ++ds) {
      u16x8 t = *(const u16x8*)(qp + ds*16);
      u16x8 r;
#pragma unroll
      for (int j = 0; j < 8; ++j) r[j] = f2bf(bf2f(t[j]) * qscale);
      qf[ds] = *(bf16x8*)&r;
    }
  }
  f32x16 o0 = {}, o1 = {}, o2 = {}, o3 = {};   // O dh-subtiles 0..3
  float m_run = -INFINITY, l_run = 0.f;

  const char* Kg = (const char*)(K + (size_t)b*NS*ND + h*NDH);
  const char* Vg = (const char*)(V + (size_t)b*NS*ND + h*NDH);
  const int ROWB = ND * 2;

  int p   = tid & 31;    // dh pair for V repack
  int kvg = tid >> 5;    // kv chunk 0..15 (4 kv rows each)

  auto issueKV = [&](int kv0, int buf, unsigned (&dlo)[4], unsigned (&dhi)[4]) {
    const char* vrow = Vg + (size_t)(kv0 + kvg*4) * ROWB;
#pragma unroll
    for (int j = 0; j < 4; ++j) {
      dlo[j] = *(const unsigned*)(vrow + j*ROWB + p*4);
      dhi[j] = *(const unsigned*)(vrow + j*ROWB + 128 + p*4);
    }
    char* ksb = (char*)Ks + buf*16384;
#pragma unroll
    for (int c = 0; c < 2; ++c) {
      int s = c*8192 + wv*1024 + lane*16;
      int row = s >> 8;
      int within = (s & 255) ^ ((row & 7) << 4);
      gld16(Kg + (size_t)(kv0 + row)*ROWB + within, ksb + c*8192 + wv*1024);
    }
    __builtin_amdgcn_sched_barrier(0);
  };

  auto dostep = [&](int kv0, int buf, const unsigned (&dlo)[4], const unsigned (&dhi)[4],
                    bool hasNext) {
    if (hasNext) asm volatile("s_waitcnt vmcnt(10)" ::: "memory");
    else         asm volatile("s_waitcnt vmcnt(0)"  ::: "memory");
    __builtin_amdgcn_sched_barrier(0);
    __builtin_amdgcn_s_barrier();        // BAR-A: all waves' K(t) landed
    __builtin_amdgcn_sched_barrier(0);

    char* vtb = (char*)Vt + buf*16384;
    const char* ksb = (const char*)Ks + buf*16384;

    // Vt write: rows {2p,2p+1,2p+64,2p+65} all swizzle to granule p&7
    {
      u16x4 rA, rB, rC, rD;
#pragma unroll
      for (int j = 0; j < 4; ++j) {
        rA[j] = (u16)dlo[j]; rB[j] = (u16)(dlo[j] >> 16);
        rC[j] = (u16)dhi[j]; rD[j] = (u16)(dhi[j] >> 16);
      }
      int ws = (p & 7) << 4;
      int a0 = ((2*p   )*128 + kvg*8) ^ ws;
      int a1 = ((2*p+ 1)*128 + kvg*8) ^ ws;
      int a2 = ((2*p+64)*128 + kvg*8) ^ ws;
      int a3 = ((2*p+65)*128 + kvg*8) ^ ws;
      *(u16x4*)(vtb + a0) = rA;
      *(u16x4*)(vtb + a1) = rB;
      *(u16x4*)(vtb + a2) = rC;
      *(u16x4*)(vtb + a3) = rD;
    }

    // S = K Q^T (swapped): p0 = kv 0..31, p1 = kv 32..63; lane's q = ql
    f32x16 p0 = {}, p1 = {};
    __builtin_amdgcn_s_setprio(1);
#pragma unroll
    for (int ds = 0; ds < 8; ++ds) {
      bf16x8 kf0 = *(const bf16x8*)(ksb + ((ql*256 + ds*32 + hi*16) ^ swzl));
      p0 = mfma32_bf16(kf0, qf[ds], p0);
      bf16x8 kf1 = *(const bf16x8*)(ksb + (((32+ql)*256 + ds*32 + hi*16) ^ swzl));
      p1 = mfma32_bf16(kf1, qf[ds], p1);
    }
    __builtin_amdgcn_s_setprio(0);

    // causal mask
    if (kv0 + 63 > qw) {
      int thresh = qa - kv0 - 4*hi;
#pragma unroll
      for (int r = 0; r < 16; ++r) {
        int c0 = (r & 3) + 8*(r >> 2);
        p0[r] = (c0      > thresh) ? -INFINITY : p0[r];
        p1[r] = (c0 + 32 > thresh) ? -INFINITY : p1[r];
      }
    }

    // row max (in-reg tree + one cross-pair shuffle)
    float mx[16];
#pragma unroll
    for (int r = 0; r < 16; ++r) mx[r] = fmaxf(p0[r], p1[r]);
#pragma unroll
    for (int s = 8; s > 0; s >>= 1)
#pragma unroll
      for (int r = 0; r < 8; ++r) if (r < s) mx[r] = fmaxf(mx[r], mx[r + s]);
    float pmax = fmaxf(mx[0], __shfl_xor(mx[0], 32, 64));

    // T13 defer-max
    if (!__all(pmax <= m_run + 8.f)) {
      float mn = fmaxf(m_run, pmax);
      float corr = __builtin_amdgcn_exp2f(m_run - mn);
      m_run = mn; l_run *= corr;
#pragma unroll
      for (int r = 0; r < 16; ++r) {
        float cw = __shfl(corr, (r & 3) + 8*(r >> 2) + 4*hi, 64);
        o0[r] *= cw; o1[r] *= cw; o2[r] *= cw; o3[r] *= cw;
      }
    }

    // exp2 + row sum
    float sm[16];
#pragma unroll
    for (int r = 0; r < 16; ++r) {
      p0[r] = __builtin_amdgcn_exp2f(p0[r] - m_run);
      p1[r] = __builtin_amdgcn_exp2f(p1[r] - m_run);
      sm[r] = p0[r] + p1[r];
    }
#pragma unroll
    for (int s = 8; s > 0; s >>= 1)
#pragma unroll
      for (int r = 0; r < 8; ++r) if (r < s) sm[r] += sm[r + s];
    l_run += sm[0] + __shfl_xor(sm[0], 32, 64);

    // P -> bf16 A-frags: 16 cvt_pk + 8 permlane32_swap (T12)
    bf16x8 pa0, pa1, pa2, pa3;
#define MKPA(P, B, OUT) {                              \
      unsigned a0 = cvtpk(P[(B)+0], P[(B)+1]);         \
      unsigned b0 = cvtpk(P[(B)+4], P[(B)+5]);         \
      p32swap(a0, b0);                                 \
      unsigned a1 = cvtpk(P[(B)+2], P[(B)+3]);         \
      unsigned b1 = cvtpk(P[(B)+6], P[(B)+7]);         \
      p32swap(a1, b1);                                 \
      u32x4_t w; w[0]=a0; w[1]=a1; w[2]=b0; w[3]=b1;   \
      OUT = *(bf16x8*)&w; }
    MKPA(p0, 0, pa0)
    MKPA(p0, 8, pa1)
    MKPA(p1, 0, pa2)
    MKPA(p1, 8, pa3)
#undef MKPA

    asm volatile("s_waitcnt lgkmcnt(0)" ::: "memory");  // my Vt writes done
    __builtin_amdgcn_sched_barrier(0);
    __builtin_amdgcn_s_barrier();        // BAR-B: all waves' Vt[buf] visible
    __builtin_amdgcn_sched_barrier(0);

    // O += P V
    __builtin_amdgcn_s_setprio(1);
#define PVT(OT, T) {                                                        \
      _Pragma("unroll")                                                     \
      for (int ks = 0; ks < 4; ++ks) {                                      \
        int a = ((((T)*32 + ql)*128 + ks*32 + hi*16) ^ vswz);               \
        bf16x8 vf = *(const bf16x8*)(vtb + a);                              \
        OT = mfma32_bf16(ks==0?pa0:ks==1?pa1:ks==2?pa2:pa3, vf, OT);        \
      } }
    PVT(o0, 0)
    PVT(o1, 1)
    PVT(o2, 2)
    PVT(o3, 3)
#undef PVT
    __builtin_amdgcn_s_setprio(0);
  };

  int nt = 4*qt + 4;                     // kv tiles 0 .. q0+255
  unsigned dloA[4], dhiA[4], dloB[4], dhiB[4];
  issueKV(0, 0, dloA, dhiA);
  for (int t = 0; ; t += 2) {
    bool h1 = (t+1 < nt);
    if (h1) issueKV((t+1)*64, 1, dloB, dhiB);
    dostep(t*64, 0, dloA, dhiA, h1);
    if (!h1) break;
    bool h2 = (t+2 < nt);
    if (h2) issueKV((t+2)*64, 0, dloA, dhiA);
    dostep((t+1)*64, 1, dloB, dhiB, h2);
    if (!h2) break;
  }

  // epilogue
  float inv = 1.0f / l_run;
#pragma unroll
  for (int r = 0; r < 16; ++r) {
    int crow = (r & 3) + 8*(r >> 2) + 4*hi;
    float iv = __shfl(inv, crow, 64);
    size_t base = (size_t)(b*NS + qw + crow) * ND + h*NDH + ql;
    O[base +  0] = f2bf(o0[r] * iv);
    O[base + 32] = f2bf(o1[r] * iv);
    O[base + 64] = f2bf(o2[r] * iv);
    O[base + 96] = f2bf(o3[r] * iv);
  }
}

// ---------------- launch ----------------
extern "C" void kernel_launch(void* const* d_in, const int* in_sizes, int n_in,
                              void* d_out, int out_size, void* d_ws, size_t ws_size,
                              hipStream_t stream) {
  const float* x  = (const float*)d_in[0];
  // d_in[1] = attn_mask (causal, handled analytically)
  const float* Wq = (const float*)d_in[2];
  const float* Wk = (const float*)d_in[3];
  const float* Wv = (const float*)d_in[4];
  const float* Wo = (const float*)d_in[5];

  char* ws = (char*)d_ws;
  const size_t SZ_MD = (size_t)NM * ND * 2;
  const size_t SZ_W  = (size_t)ND * ND * 2;
  u16* xb  = (u16*)(ws);
  u16* Qb  = (u16*)(ws + SZ_MD);
  u16* Kb  = (u16*)(ws + 2*SZ_MD);
  u16* Vb  = (u16*)(ws + 3*SZ_MD);
  u16* Ab  = (u16*)(ws + 4*SZ_MD);
  u16* Wqb = (u16*)(ws + 5*SZ_MD);
  u16* Wkb = (u16*)(ws + 5*SZ_MD + SZ_W);
  u16* Wvb = (u16*)(ws + 5*SZ_MD + 2*SZ_W);
  u16* Wob = (u16*)(ws + 5*SZ_MD + 3*SZ_W);
  float* cosT = (float*)(ws + 5*SZ_MD + 4*SZ_W);
  float* sinT = (float*)(ws + 5*SZ_MD + 4*SZ_W + (size_t)NS*64*4);
  size_t needed = 5*SZ_MD + 4*SZ_W + 2*(size_t)NS*64*4;
  if (ws_size < needed) return;

  {
    int n8 = (NM * ND) / 8;
    cvt_bf16_kernel<<<(n8 + 255)/256, 256, 0, stream>>>(x, xb, n8);
    int w8 = (ND * ND) / 8;
    cvt_bf16_kernel<<<(w8 + 255)/256, 256, 0, stream>>>(Wq, Wqb, w8);
    cvt_bf16_kernel<<<(w8 + 255)/256, 256, 0, stream>>>(Wk, Wkb, w8);
    cvt_bf16_kernel<<<(w8 + 255)/256, 256, 0, stream>>>(Wv, Wvb, w8);
    cvt_bf16_kernel<<<(w8 + 255)/256, 256, 0, stream>>>(Wo, Wob, w8);
  }
  rope_tables_kernel<<<NS, 64, 0, stream>>>(cosT, sinT);

  // fused QKV projection: one dispatch, 768 blocks
  gemm256_kernel<u16><<<3*256, 512, 0, stream>>>(xb, Wqb, Wkb, Wvb,
                                                 Qb, Kb, Vb, ND, ND);

  {
    int nthr = NM * NH * 8;
    rope_apply_kernel<<<nthr/256, 256, 0, stream>>>(Qb, cosT, sinT);
    rope_apply_kernel<<<nthr/256, 256, 0, stream>>>(Kb, cosT, sinT);
  }

  flash_attn_kernel<<<dim3(NB*NH, NS/256), 512, 0, stream>>>(Qb, Kb, Vb, Ab);

  gemm256_kernel<float><<<256, 512, 0, stream>>>(Ab, Wob, nullptr, nullptr,
                                                 (float*)d_out, nullptr, nullptr, ND, ND);
}

// Round 13
// 413.415 us; speedup vs baseline: 1.1470x; 1.0139x over previous
//
#include <hip/hip_runtime.h>
#include <cstdint>
#include <cmath>

#define NB 4
#define NS 2048
#define ND 2048
#define NH 16
#define NDH 128
#define NM (NB*NS)   // 8192

typedef unsigned short u16;
typedef __bf16 bf16x8 __attribute__((ext_vector_type(8)));
typedef u16    u16x8  __attribute__((ext_vector_type(8)));
typedef u16    u16x4  __attribute__((ext_vector_type(4)));
typedef float  f32x4  __attribute__((ext_vector_type(4)));
typedef float  f32x16 __attribute__((ext_vector_type(16)));
typedef unsigned u32x4_t __attribute__((ext_vector_type(4)));

__device__ __forceinline__ u16 f2bf(float f) {
  unsigned u = __float_as_uint(f);
  u += 0x7fffu + ((u >> 16) & 1u);   // RNE
  return (u16)(u >> 16);
}
__device__ __forceinline__ float bf2f(u16 h) {
  return __uint_as_float(((unsigned)h) << 16);
}
__device__ __forceinline__ void gld16(const void* g, void* l) {
  __builtin_amdgcn_global_load_lds((__attribute__((address_space(1))) void*)g,
                                   (__attribute__((address_space(3))) void*)l,
                                   16, 0, 0);
}
__device__ __forceinline__ f32x4 mfma_bf16(bf16x8 a, bf16x8 b, f32x4 c) {
  return __builtin_amdgcn_mfma_f32_16x16x32_bf16(a, b, c, 0, 0, 0);
}
__device__ __forceinline__ f32x16 mfma32_bf16(bf16x8 a, bf16x8 b, f32x16 c) {
  return __builtin_amdgcn_mfma_f32_32x32x16_bf16(a, b, c, 0, 0, 0);
}
__device__ __forceinline__ unsigned cvtpk(float lo, float hi) {
  unsigned r;
  asm("v_cvt_pk_bf16_f32 %0, %1, %2" : "=v"(r) : "v"(lo), "v"(hi));
  return r;
}
__device__ __forceinline__ void p32swap(unsigned &a, unsigned &b) {
  asm volatile("v_permlane32_swap_b32 %0, %1" : "+v"(a), "+v"(b));
}

// ---------------- fp32 -> bf16 convert (8 elems/thread) ----------------
__global__ void cvt_bf16_kernel(const float* __restrict__ in, u16* __restrict__ out, int n8) {
  int i = blockIdx.x * 256 + threadIdx.x;
  if (i >= n8) return;
  const float4* p = (const float4*)in + (size_t)i * 2;
  float4 a = p[0], b = p[1];
  u16x8 r;
  r[0]=f2bf(a.x); r[1]=f2bf(a.y); r[2]=f2bf(a.z); r[3]=f2bf(a.w);
  r[4]=f2bf(b.x); r[5]=f2bf(b.y); r[6]=f2bf(b.z); r[7]=f2bf(b.w);
  ((u16x8*)out)[i] = r;
}

// 4 weight matrices in one dispatch
__global__ void cvt4_bf16_kernel(const float* __restrict__ i0, const float* __restrict__ i1,
                                 const float* __restrict__ i2, const float* __restrict__ i3,
                                 u16* o0, u16* o1, u16* o2, u16* o3, int n8each) {
  int idx = blockIdx.x * 256 + threadIdx.x;
  int w = idx / n8each, i = idx - w * n8each;
  if (w >= 4) return;
  const float* in = (w == 0) ? i0 : (w == 1) ? i1 : (w == 2) ? i2 : i3;
  u16* out = (w == 0) ? o0 : (w == 1) ? o1 : (w == 2) ? o2 : o3;
  const float4* p = (const float4*)in + (size_t)i * 2;
  float4 a = p[0], b = p[1];
  u16x8 r;
  r[0]=f2bf(a.x); r[1]=f2bf(a.y); r[2]=f2bf(a.z); r[3]=f2bf(a.w);
  r[4]=f2bf(b.x); r[5]=f2bf(b.y); r[6]=f2bf(b.z); r[7]=f2bf(b.w);
  ((u16x8*)out)[i] = r;
}

// ---------------- RoPE tables: cos/sin [S][64] ----------------
__global__ void rope_tables_kernel(float* __restrict__ cosT, float* __restrict__ sinT) {
  int s = blockIdx.x, d = threadIdx.x;
  double inv = pow(10000.0, -(double)d / 64.0);
  float ang = (float)((double)s * inv);
  cosT[s*64 + d] = cosf(ang);
  sinT[s*64 + d] = sinf(ang);
}

// ---------------- RoPE apply, Q and K in one dispatch ----------------
__global__ void rope_apply_kernel(u16* __restrict__ Qb, u16* __restrict__ Kb,
                                  const float* __restrict__ cosT,
                                  const float* __restrict__ sinT, int nthr) {
  int gidx = blockIdx.x * 256 + threadIdx.x;
  u16* X = (gidx < nthr) ? Qb : Kb;
  int idx = (gidx < nthr) ? gidx : gidx - nthr;
  int pc = idx & 7, h = (idx >> 3) & (NH - 1), m = idx >> 7;
  int s = m & (NS - 1);
  int d0 = pc * 8;
  size_t base = (size_t)m * ND + h * NDH + d0;
  u16x8 v0 = *(const u16x8*)(X + base);
  u16x8 v1 = *(const u16x8*)(X + base + 64);
  u16x8 r0, r1;
#pragma unroll
  for (int j = 0; j < 8; ++j) {
    float c  = cosT[s*64 + d0 + j];
    float sn = sinT[s*64 + d0 + j];
    float x0 = bf2f(v0[j]), x1 = bf2f(v1[j]);
    r0[j] = f2bf(x0 * c - x1 * sn);
    r1[j] = f2bf(x1 * c + x0 * sn);
  }
  *(u16x8*)(X + base)      = r0;
  *(u16x8*)(X + base + 64) = r1;
}

// ---------------- bf16 GEMM, 256x256 tile, 8-phase, 16x16x32 MFMA ----------
// R13: barrier thinning — barriers only at even phases (P2/P4/P6/P8).
// WAR audit (stage target slab vs its last LDS-read):
//   P3 stageA(b0,k0): last read P2  | barrier@P2 separates
//   P4 stageB(b0,k0): last read P1  | barrier@P2
//   P5 stageA(b0,k1): last read P4  | barrier@P4
//   P6 stageB(b0,k1): last read P3  | barrier@P4
//   P7 stageA(b1,k0): last read P6  | barrier@P6
//   P8 stageB(b1,k0): last read P5  | barrier@P6
//   P1' stageA(b1,k1): last read P8 | barrier@P8
//   P2' stageB(b1,k1): last read P7 | barrier@P8
// A reader finishes its LDS reads before arriving at a barrier (lgkmcnt
// precedes its MFMA); a stager passes that barrier only after all readers
// arrive.  vmcnt(4) ledger unchanged from R8 (per-wave gld16 order kept).
// Within each 2-phase window, waves drift and the compiler hoists the even
// phase's ds_reads over the odd phase's MFMA -> LDS/MFMA overlap.
#define BARX do { __builtin_amdgcn_s_barrier(); __builtin_amdgcn_sched_barrier(0); } while (0)
#define VM4  do { asm volatile("s_waitcnt vmcnt(4)" ::: "memory"); \
                  __builtin_amdgcn_sched_barrier(0); } while (0)
#define GP(BUF, KS, MH, LOADB, WAITV, DOBAR, STAGE) do {                          \
  bf16x8 af[4];                                                                   \
  _Pragma("unroll")                                                               \
  for (int mf = 0; mf < 4; ++mf)                                                  \
    af[mf] = *(const bf16x8*)(Asb + (BUF)*32768 + (KS)*16384 + arow + ((MH)*4+mf)*1024); \
  if (LOADB) {                                                                    \
    _Pragma("unroll")                                                             \
    for (int nf = 0; nf < 4; ++nf)                                                \
      bfr[nf] = *(const bf16x8*)(Bsb + (BUF)*32768 + (KS)*16384 + brow + nf*1024); \
  }                                                                               \
  STAGE;                                                                          \
  __builtin_amdgcn_s_setprio(1);                                                  \
  _Pragma("unroll")                                                               \
  for (int mf = 0; mf < 4; ++mf)                                                  \
    _Pragma("unroll")                                                             \
    for (int nf = 0; nf < 4; ++nf)                                                \
      acc[(MH)*4+mf][nf] = mfma_bf16(af[mf], bfr[nf], acc[(MH)*4+mf][nf]);        \
  __builtin_amdgcn_s_setprio(0);                                                  \
  if (WAITV) VM4;                                                                 \
  if (DOBAR) BARX;                                                                \
} while (0)

template <typename OutT>
__global__ __launch_bounds__(512, 2) void gemm256_kernel(
    const u16* __restrict__ A,
    const u16* __restrict__ B0, const u16* __restrict__ B1, const u16* __restrict__ B2,
    OutT* __restrict__ C0, OutT* __restrict__ C1, OutT* __restrict__ C2,
    int Nd, int Kd) {
  __shared__ __align__(16) char Asb[65536];
  __shared__ __align__(16) char Bsb[65536];
  int tid = threadIdx.x;
  int wave = tid >> 6, lane = tid & 63;
  int li = lane & 15, lg = lane >> 4;
  int wr = wave >> 2, wc = wave & 3;           // 2 x 4 wave grid
  int w  = (int)blockIdx.x >> 8;               // matrix select (fused QKV)
  int tb = (int)blockIdx.x & 255;
  const u16* Bw = (w == 0) ? B0 : (w == 1) ? B1 : B2;
  OutT*      C  = (w == 0) ? C0 : (w == 1) ? C1 : C2;
  int NTn = Nd >> 8;
  int swz = (tb & 7) * 32 + (tb >> 3);         // XCD swizzle over 256 tiles
  int m0 = (swz / NTn) << 8, n0 = (swz % NTn) << 8;

  // ds_read per-lane bases: swizzle keyed on row bits 1..2
  int rswz = (lg * 16) ^ (((li >> 1) & 3) << 4);
  int arow = (wr * 128 + li) * 64 + rswz;      // + (MH*4+mf)*1024
  int brow = (wc *  64 + li) * 64 + rswz;      // + nf*1024

  // staging: physical byte p of row r holds logical p ^ (((r>>1)&3)<<4)
  int srow = wave * 16 + (lane >> 2);
  int scswz = ((lane & 3) * 16) ^ (((srow >> 1) & 3) << 4);
  size_t rowB = (size_t)Kd * 2;
  const char* Asrc = (const char*)A  + (size_t)(m0 + srow) * rowB + scswz;
  const char* Bsrc = (const char*)Bw + (size_t)(n0 + srow) * rowB + scswz;
  char* Adst = Asb + wave * 1024;
  char* Bdst = Bsb + wave * 1024;
  size_t half2 = rowB << 7;                    // +128 rows (same swz: 128%4==0)

  auto stageA = [&](int buf, int ks, int tile) {
    const char* s = Asrc + (size_t)tile * 128 + ks * 64;
    char* d = Adst + buf * 32768 + ks * 16384;
    gld16(s, d);
    gld16(s + half2, d + 8192);
  };
  auto stageB = [&](int buf, int ks, int tile) {
    const char* s = Bsrc + (size_t)tile * 128 + ks * 64;
    char* d = Bdst + buf * 32768 + ks * 16384;
    gld16(s, d);
    gld16(s + half2, d + 8192);
  };

  f32x4 acc[8][4] = {};
  bf16x8 bfr[4];

  int NKT = Kd >> 6;          // K-tiles of 64
  int NIT = NKT >> 1;         // 2 tiles per iteration

  // prologue: tile0 fully + tile1 ks0 (12 loads); vmcnt(4) -> tile0 landed
  stageA(0, 0, 0); stageA(0, 1, 0); stageB(0, 0, 0); stageB(0, 1, 0);
  stageA(1, 0, 1); stageB(1, 0, 1);
  asm volatile("s_waitcnt vmcnt(4)" ::: "memory");
  __builtin_amdgcn_sched_barrier(0);
  BARX;

  for (int j = 0; j < NIT; ++j) {
    int t1  = 2*j + 1;
    int tn0 = (2*j + 2) & (NKT - 1);   // wraps on final iters (garbage, unconsumed)
    int tn1 = (2*j + 3) & (NKT - 1);
    GP(0, 0, 0, true,  false, false, { stageA(1, 1, t1);  });
    GP(0, 0, 1, false, false, true,  { stageB(1, 1, t1);  });
    GP(0, 1, 1, true,  false, false, { stageA(0, 0, tn0); });
    GP(0, 1, 0, false, true,  true,  { stageB(0, 0, tn0); });
    GP(1, 0, 0, true,  false, false, { stageA(0, 1, tn0); });
    GP(1, 0, 1, false, false, true,  { stageB(0, 1, tn0); });
    GP(1, 1, 1, true,  false, false, { stageA(1, 0, tn1); });
    GP(1, 1, 0, false, true,  true,  { stageB(1, 0, tn1); });
  }
  asm volatile("s_waitcnt vmcnt(0)" ::: "memory");   // drain dangling stages

  // epilogue: C layout col = lane&15, row = (lane>>4)*4 + reg  [m89/m91]
  int rbase = m0 + wr*128 + lg*4;
  int cbase = n0 + wc*64 + li;
#pragma unroll
  for (int am = 0; am < 8; ++am)
#pragma unroll
    for (int nf = 0; nf < 4; ++nf)
#pragma unroll
      for (int r = 0; r < 4; ++r) {
        size_t off = (size_t)(rbase + am*16 + r) * Nd + (cbase + nf*16);
        if constexpr (sizeof(OutT) == 2) C[off] = f2bf(acc[am][nf][r]);
        else                             C[off] = acc[am][nf][r];
      }
}

// ---------------- causal flash attention, 32x32 swapped-QK^T ----------------
__global__ __launch_bounds__(512, 2) void flash_attn_kernel(
    const u16* __restrict__ Q, const u16* __restrict__ K, const u16* __restrict__ V,
    u16* __restrict__ O) {
  __shared__ __align__(16) u16 Ks[2*64*128];  // 32 KB swizzled [kv][dh]
  __shared__ __align__(16) u16 Vt[2*128*64];  // 32 KB swizzled [dh][kv]
  int tid = threadIdx.x, wv = tid >> 6, lane = tid & 63;
  int ql = lane & 31, hi = lane >> 5;
  int b = blockIdx.x >> 4, h = blockIdx.x & 15;
  int qt = (int)gridDim.y - 1 - (int)blockIdx.y;
  int q0 = qt << 8;
  int qw = q0 + wv*32;          // wave q base
  int qa = qw + ql;             // this lane's q row
  int swzl = (ql & 7) << 4;     // Ks swizzle (256-B rows)
  int vswz = ((ql >> 1) & 7) << 4;  // Vt read swizzle (128-B rows, bits 1..3)
  const float qscale = 0.08838834764831845f * 1.4426950408889634f; // /sqrt(128)*log2e

  bf16x8 qf[8];
  {
    const u16* qp = Q + (size_t)(b*NS + qa) * ND + h*NDH + hi*8;
#pragma unroll
    for (int ds = 0; ds < 8; ++ds) {
      u16x8 t = *(const u16x8*)(qp + ds*16);
      u16x8 r;
#pragma unroll
      for (int j = 0; j < 8; ++j) r[j] = f2bf(bf2f(t[j]) * qscale);
      qf[ds] = *(bf16x8*)&r;
    }
  }
  f32x16 o0 = {}, o1 = {}, o2 = {}, o3 = {};   // O dh-subtiles 0..3
  float m_run = -INFINITY, l_run = 0.f;

  const char* Kg = (const char*)(K + (size_t)b*NS*ND + h*NDH);
  const char* Vg = (const char*)(V + (size_t)b*NS*ND + h*NDH);
  const int ROWB = ND * 2;

  int p   = tid & 31;    // dh pair for V repack
  int kvg = tid >> 5;    // kv chunk 0..15 (4 kv rows each)

  auto issueKV = [&](int kv0, int buf, unsigned (&dlo)[4], unsigned (&dhi)[4]) {
    const char* vrow = Vg + (size_t)(kv0 + kvg*4) * ROWB;
#pragma unroll
    for (int j = 0; j < 4; ++j) {
      dlo[j] = *(const unsigned*)(vrow + j*ROWB + p*4);
      dhi[j] = *(const unsigned*)(vrow + j*ROWB + 128 + p*4);
    }
    char* ksb = (char*)Ks + buf*16384;
#pragma unroll
    for (int c = 0; c < 2; ++c) {
      int s = c*8192 + wv*1024 + lane*16;
      int row = s >> 8;
      int within = (s & 255) ^ ((row & 7) << 4);
      gld16(Kg + (size_t)(kv0 + row)*ROWB + within, ksb + c*8192 + wv*1024);
    }
    __builtin_amdgcn_sched_barrier(0);
  };

  auto dostep = [&](int kv0, int buf, const unsigned (&dlo)[4], const unsigned (&dhi)[4],
                    bool hasNext) {
    if (hasNext) asm volatile("s_waitcnt vmcnt(10)" ::: "memory");
    else         asm volatile("s_waitcnt vmcnt(0)"  ::: "memory");
    __builtin_amdgcn_sched_barrier(0);
    __builtin_amdgcn_s_barrier();        // BAR-A: all waves' K(t) landed
    __builtin_amdgcn_sched_barrier(0);

    char* vtb = (char*)Vt + buf*16384;
    const char* ksb = (const char*)Ks + buf*16384;

    // Vt write: rows {2p,2p+1,2p+64,2p+65} all swizzle to granule p&7
    {
      u16x4 rA, rB, rC, rD;
#pragma unroll
      for (int j = 0; j < 4; ++j) {
        rA[j] = (u16)dlo[j]; rB[j] = (u16)(dlo[j] >> 16);
        rC[j] = (u16)dhi[j]; rD[j] = (u16)(dhi[j] >> 16);
      }
      int ws = (p & 7) << 4;
      int a0 = ((2*p   )*128 + kvg*8) ^ ws;
      int a1 = ((2*p+ 1)*128 + kvg*8) ^ ws;
      int a2 = ((2*p+64)*128 + kvg*8) ^ ws;
      int a3 = ((2*p+65)*128 + kvg*8) ^ ws;
      *(u16x4*)(vtb + a0) = rA;
      *(u16x4*)(vtb + a1) = rB;
      *(u16x4*)(vtb + a2) = rC;
      *(u16x4*)(vtb + a3) = rD;
    }

    // S = K Q^T (swapped): p0 = kv 0..31, p1 = kv 32..63; lane's q = ql
    f32x16 p0 = {}, p1 = {};
    __builtin_amdgcn_s_setprio(1);
#pragma unroll
    for (int ds = 0; ds < 8; ++ds) {
      bf16x8 kf0 = *(const bf16x8*)(ksb + ((ql*256 + ds*32 + hi*16) ^ swzl));
      p0 = mfma32_bf16(kf0, qf[ds], p0);
      bf16x8 kf1 = *(const bf16x8*)(ksb + (((32+ql)*256 + ds*32 + hi*16) ^ swzl));
      p1 = mfma32_bf16(kf1, qf[ds], p1);
    }
    __builtin_amdgcn_s_setprio(0);

    // causal mask
    if (kv0 + 63 > qw) {
      int thresh = qa - kv0 - 4*hi;
#pragma unroll
      for (int r = 0; r < 16; ++r) {
        int c0 = (r & 3) + 8*(r >> 2);
        p0[r] = (c0      > thresh) ? -INFINITY : p0[r];
        p1[r] = (c0 + 32 > thresh) ? -INFINITY : p1[r];
      }
    }

    // row max (in-reg tree + one cross-pair shuffle)
    float mx[16];
#pragma unroll
    for (int r = 0; r < 16; ++r) mx[r] = fmaxf(p0[r], p1[r]);
#pragma unroll
    for (int s = 8; s > 0; s >>= 1)
#pragma unroll
      for (int r = 0; r < 8; ++r) if (r < s) mx[r] = fmaxf(mx[r], mx[r + s]);
    float pmax = fmaxf(mx[0], __shfl_xor(mx[0], 32, 64));

    // T13 defer-max
    if (!__all(pmax <= m_run + 8.f)) {
      float mn = fmaxf(m_run, pmax);
      float corr = __builtin_amdgcn_exp2f(m_run - mn);
      m_run = mn; l_run *= corr;
#pragma unroll
      for (int r = 0; r < 16; ++r) {
        float cw = __shfl(corr, (r & 3) + 8*(r >> 2) + 4*hi, 64);
        o0[r] *= cw; o1[r] *= cw; o2[r] *= cw; o3[r] *= cw;
      }
    }

    // exp2 + row sum
    float sm[16];
#pragma unroll
    for (int r = 0; r < 16; ++r) {
      p0[r] = __builtin_amdgcn_exp2f(p0[r] - m_run);
      p1[r] = __builtin_amdgcn_exp2f(p1[r] - m_run);
      sm[r] = p0[r] + p1[r];
    }
#pragma unroll
    for (int s = 8; s > 0; s >>= 1)
#pragma unroll
      for (int r = 0; r < 8; ++r) if (r < s) sm[r] += sm[r + s];
    l_run += sm[0] + __shfl_xor(sm[0], 32, 64);

    // P -> bf16 A-frags: 16 cvt_pk + 8 permlane32_swap (T12)
    bf16x8 pa0, pa1, pa2, pa3;
#define MKPA(P, B, OUT) {                              \
      unsigned a0 = cvtpk(P[(B)+0], P[(B)+1]);         \
      unsigned b0 = cvtpk(P[(B)+4], P[(B)+5]);         \
      p32swap(a0, b0);                                 \
      unsigned a1 = cvtpk(P[(B)+2], P[(B)+3]);         \
      unsigned b1 = cvtpk(P[(B)+6], P[(B)+7]);         \
      p32swap(a1, b1);                                 \
      u32x4_t w; w[0]=a0; w[1]=a1; w[2]=b0; w[3]=b1;   \
      OUT = *(bf16x8*)&w; }
    MKPA(p0, 0, pa0)
    MKPA(p0, 8, pa1)
    MKPA(p1, 0, pa2)
    MKPA(p1, 8, pa3)
#undef MKPA

    asm volatile("s_waitcnt lgkmcnt(0)" ::: "memory");  // my Vt writes done
    __builtin_amdgcn_sched_barrier(0);
    __builtin_amdgcn_s_barrier();        // BAR-B: all waves' Vt[buf] visible
    __builtin_amdgcn_sched_barrier(0);

    // O += P V
    __builtin_amdgcn_s_setprio(1);
#define PVT(OT, T) {                                                        \
      _Pragma("unroll")                                                     \
      for (int ks = 0; ks < 4; ++ks) {                                      \
        int a = ((((T)*32 + ql)*128 + ks*32 + hi*16) ^ vswz);               \
        bf16x8 vf = *(const bf16x8*)(vtb + a);                              \
        OT = mfma32_bf16(ks==0?pa0:ks==1?pa1:ks==2?pa2:pa3, vf, OT);        \
      } }
    PVT(o0, 0)
    PVT(o1, 1)
    PVT(o2, 2)
    PVT(o3, 3)
#undef PVT
    __builtin_amdgcn_s_setprio(0);
  };

  int nt = 4*qt + 4;                     // kv tiles 0 .. q0+255
  unsigned dloA[4], dhiA[4], dloB[4], dhiB[4];
  issueKV(0, 0, dloA, dhiA);
  for (int t = 0; ; t += 2) {
    bool h1 = (t+1 < nt);
    if (h1) issueKV((t+1)*64, 1, dloB, dhiB);
    dostep(t*64, 0, dloA, dhiA, h1);
    if (!h1) break;
    bool h2 = (t+2 < nt);
    if (h2) issueKV((t+2)*64, 0, dloA, dhiA);
    dostep((t+1)*64, 1, dloB, dhiB, h2);
    if (!h2) break;
  }

  // epilogue
  float inv = 1.0f / l_run;
#pragma unroll
  for (int r = 0; r < 16; ++r) {
    int crow = (r & 3) + 8*(r >> 2) + 4*hi;
    float iv = __shfl(inv, crow, 64);
    size_t base = (size_t)(b*NS + qw + crow) * ND + h*NDH + ql;
    O[base +  0] = f2bf(o0[r] * iv);
    O[base + 32] = f2bf(o1[r] * iv);
    O[base + 64] = f2bf(o2[r] * iv);
    O[base + 96] = f2bf(o3[r] * iv);
  }
}

// ---------------- launch ----------------
extern "C" void kernel_launch(void* const* d_in, const int* in_sizes, int n_in,
                              void* d_out, int out_size, void* d_ws, size_t ws_size,
                              hipStream_t stream) {
  const float* x  = (const float*)d_in[0];
  // d_in[1] = attn_mask (causal, handled analytically)
  const float* Wq = (const float*)d_in[2];
  const float* Wk = (const float*)d_in[3];
  const float* Wv = (const float*)d_in[4];
  const float* Wo = (const float*)d_in[5];

  char* ws = (char*)d_ws;
  const size_t SZ_MD = (size_t)NM * ND * 2;
  const size_t SZ_W  = (size_t)ND * ND * 2;
  u16* xb  = (u16*)(ws);
  u16* Qb  = (u16*)(ws + SZ_MD);
  u16* Kb  = (u16*)(ws + 2*SZ_MD);
  u16* Vb  = (u16*)(ws + 3*SZ_MD);
  u16* Ab  = (u16*)(ws + 4*SZ_MD);
  u16* Wqb = (u16*)(ws + 5*SZ_MD);
  u16* Wkb = (u16*)(ws + 5*SZ_MD + SZ_W);
  u16* Wvb = (u16*)(ws + 5*SZ_MD + 2*SZ_W);
  u16* Wob = (u16*)(ws + 5*SZ_MD + 3*SZ_W);
  float* cosT = (float*)(ws + 5*SZ_MD + 4*SZ_W);
  float* sinT = (float*)(ws + 5*SZ_MD + 4*SZ_W + (size_t)NS*64*4);
  size_t needed = 5*SZ_MD + 4*SZ_W + 2*(size_t)NS*64*4;
  if (ws_size < needed) return;

  {
    int n8 = (NM * ND) / 8;
    cvt_bf16_kernel<<<(n8 + 255)/256, 256, 0, stream>>>(x, xb, n8);
    int w8 = (ND * ND) / 8;
    cvt4_bf16_kernel<<<(4*w8 + 255)/256, 256, 0, stream>>>(Wq, Wk, Wv, Wo,
                                                           Wqb, Wkb, Wvb, Wob, w8);
  }
  rope_tables_kernel<<<NS, 64, 0, stream>>>(cosT, sinT);

  // fused QKV projection: one dispatch, 768 blocks
  gemm256_kernel<u16><<<3*256, 512, 0, stream>>>(xb, Wqb, Wkb, Wvb,
                                                 Qb, Kb, Vb, ND, ND);

  {
    int nthr = NM * NH * 8;
    rope_apply_kernel<<<(2*nthr)/256, 256, 0, stream>>>(Qb, Kb, cosT, sinT, nthr);
  }

  flash_attn_kernel<<<dim3(NB*NH, NS/256), 512, 0, stream>>>(Qb, Kb, Vb, Ab);

  gemm256_kernel<float><<<256, 512, 0, stream>>>(Ab, Wob, nullptr, nullptr,
                                                 (float*)d_out, nullptr, nullptr, ND, ND);
}